// Round 10
// baseline (302.166 us; speedup 1.0000x reference)
//
#include <hip/hip_runtime.h>
#include <math.h>

#define BB  4
#define NN  2000
#define TT  24
#define FIN 16
#define HH  128
#define EE  64000
#define CC  6
#define BN  (BB*NN)   // 8000

typedef _Float16 f16x8 __attribute__((ext_vector_type(8)));
typedef float f32x4 __attribute__((ext_vector_type(4)));

// ---------------- prep: [block 0] degree-hist + scan + dis | [1..256] transposes ----
// R8 BUG: launched 193 blocks -> cW1 (128x256=32768 elems, needs 128 blocks) only half
// transposed; rest was 0xAA poison => half the classifier hidden layer dead. Now 257.
__global__ __launch_bounds__(256) void prep_kernel(
    const int* __restrict__ dst,
    int* __restrict__ rowptr, int* __restrict__ cursor, float* __restrict__ dis,
    const float* __restrict__ gW1, const float* __restrict__ gW2,
    const float* __restrict__ cW1,
    float* __restrict__ o1, float* __restrict__ o2, float* __restrict__ o3)
{
    const int b = blockIdx.x;
    const int tid = threadIdx.x;
    if (b == 0) {
        __shared__ int hist[2048];
        __shared__ int part[256];
        for (int i = tid; i < 2048; i += 256) hist[i] = 0;
        __syncthreads();
        for (int i = tid; i < EE; i += 256) atomicAdd(&hist[dst[i]], 1);
        __syncthreads();
        int base = tid * 8;
        int loc[8]; int s = 0;
        #pragma unroll
        for (int u = 0; u < 8; ++u) { int v = hist[base + u]; loc[u] = s; s += v; }
        part[tid] = s;
        __syncthreads();
        #pragma unroll
        for (int off = 1; off < 256; off <<= 1) {
            int add = (tid >= off) ? part[tid - off] : 0;
            __syncthreads();
            part[tid] += add;
            __syncthreads();
        }
        int offset = (tid > 0) ? part[tid - 1] : 0;
        #pragma unroll
        for (int u = 0; u < 8; ++u) {
            int idx = base + u;
            if (idx < NN) {
                rowptr[idx] = offset + loc[u];
                cursor[idx] = offset + loc[u];
                dis[idx] = rsqrtf(fmaxf((float)hist[idx], 1.0f));
            }
        }
        if (tid == 255) rowptr[NN] = part[255];
    } else if (b <= 64) {
        int idx = (b - 1) * 256 + tid;            // gW1 128x128
        int r = idx >> 7, c = idx & 127;
        o1[c * 128 + r] = gW1[idx];
    } else if (b <= 128) {
        int idx = (b - 65) * 256 + tid;           // gW2 128x128
        int r = idx >> 7, c = idx & 127;
        o2[c * 128 + r] = gW2[idx];
    } else {
        int idx = (b - 129) * 256 + tid;          // cW1 128x256 (128 blocks)
        int r = idx >> 8, c = idx & 255;
        o3[c * 128 + r] = cW1[idx];
    }
}

// ---------------- GRU via MFMA + co-launched csr_fill ----------------
// R7 lesson: chain-depth/x-load edits neutral -> per-step serial section is bound by
// block-level parallelism (2 blocks/CU). R8/R9: 8 seqs/block -> 1000 blocks -> ~4/CU,
// LDS 17.4KB, VGPR ~64 -> up to ~31 waves/CU. A-tile rows 8-15 are zero (H rows 8-15
// kept zero; x rows not loaded); gate math guarded to lg<2. MFMA slots/CU/step double
// (half-empty tiles) but MfmaUtil 27% says the matrix pipe has the headroom.
// Blocks >= 1000 do csr_fill (125 x 512 = 64000 edges).
// NO launch_bounds min-occupancy arg (R2/R3: forced VGPR caps -> GB-scale spill).
#define HP2 136
#define GRUB 1000

__global__ __launch_bounds__(512) void gru_csr_kernel(
    const float* __restrict__ x,       // [BN][TT][FIN]
    const float* __restrict__ W_hh,    // [384][128]
    const float* __restrict__ W_ih,    // [384][16]
    const float* __restrict__ b_ih, const float* __restrict__ b_hh,
    float* __restrict__ temporal,      // [BN][HH]
    const int* __restrict__ src, const int* __restrict__ dst,
    const float* __restrict__ dis, int* __restrict__ cursor,
    int* __restrict__ esrc, float* __restrict__ enorm)
{
    const int tid  = threadIdx.x;

    if (blockIdx.x >= GRUB) {   // ---- csr_fill part ----
        int e = (blockIdx.x - GRUB) * 512 + tid;
        if (e < EE) {
            int d = dst[e], s = src[e];
            int pos = atomicAdd(&cursor[d], 1);
            esrc[pos] = s;
            enorm[pos] = dis[s] * dis[d];
        }
        return;
    }

    const int lane = tid & 63;
    const int w    = tid >> 6;
    const int l15  = lane & 15;
    const int lg   = lane >> 4;
    const int m0   = blockIdx.x * 8;
    const int u    = w * 16 + l15;

    __shared__ __align__(16) unsigned short Hhi[2][16][HP2];   // 8.7 KB (rows 8-15 stay 0)
    __shared__ __align__(16) unsigned short Hlo[2][16][HP2];   // 8.7 KB

    // ---- B-fragments: W_hh (fp16 single), 3 gates x 4 kf ----
    f16x8 Bh[3][4];
    #pragma unroll
    for (int g = 0; g < 3; ++g) {
        const int col = g * 128 + u;
        #pragma unroll
        for (int kf = 0; kf < 4; ++kf) {
            const float* wp = W_hh + col * 128 + kf * 32 + lg * 8;
            float4 c0 = *(const float4*)wp;
            float4 c1 = *(const float4*)(wp + 4);
            f16x8 b;
            b[0] = (_Float16)c0.x; b[1] = (_Float16)c0.y;
            b[2] = (_Float16)c0.z; b[3] = (_Float16)c0.w;
            b[4] = (_Float16)c1.x; b[5] = (_Float16)c1.y;
            b[6] = (_Float16)c1.z; b[7] = (_Float16)c1.w;
            Bh[g][kf] = b;
        }
    }
    // ---- B-fragments: W_ih + bias at k==16 ----
    f16x8 Bi[3];
    #pragma unroll
    for (int g = 0; g < 3; ++g) {
        const int col = g * 128 + u;
        f16x8 b;
        #pragma unroll
        for (int i = 0; i < 8; ++i) b[i] = (_Float16)0.0f;
        if (lg < 2) {
            const float* wp = W_ih + col * 16 + lg * 8;
            float4 c0 = *(const float4*)wp;
            float4 c1 = *(const float4*)(wp + 4);
            b[0] = (_Float16)c0.x; b[1] = (_Float16)c0.y;
            b[2] = (_Float16)c0.z; b[3] = (_Float16)c0.w;
            b[4] = (_Float16)c1.x; b[5] = (_Float16)c1.y;
            b[6] = (_Float16)c1.z; b[7] = (_Float16)c1.w;
        } else if (lg == 2) {
            float bias = b_ih[col] + ((g < 2) ? b_hh[col] : 0.0f);
            b[0] = (_Float16)bias;   // k == 16
        }
        Bi[g] = b;
    }

    const float bhn = b_hh[256 + u];
    float hprev[4] = {0.0f, 0.0f, 0.0f, 0.0f};

    // zero BOTH H buffers fully (rows 8-15 never written again)
    for (int i = tid; i < 2 * 16 * HP2; i += 512) {
        (&Hhi[0][0][0])[i] = 0;
        (&Hlo[0][0][0])[i] = 0;
    }
    __syncthreads();

    const f32x4 Z4 = (f32x4){0.f, 0.f, 0.f, 0.f};
    f32x4 aR0, aR1, aZ0, aZ1, aH0, aH1, aI;

    // ih for step tt (global x, rows l15<8 only); runs in barrier shadow for tt>0
#define IH_SHADOW(tt) do { \
        f16x8 axh, axl; \
        _Float16 zz = (_Float16)0.0f; \
        axh = (f16x8){zz,zz,zz,zz,zz,zz,zz,zz}; \
        axl = axh; \
        if (lg < 2 && l15 < 8) { \
            const float* xp = x + (size_t)(m0 + l15) * (TT * FIN) + (tt) * FIN + lg * 8; \
            float4 c0 = *(const float4*)xp; \
            float4 c1 = *(const float4*)(xp + 4); \
            float xv[8] = {c0.x, c0.y, c0.z, c0.w, c1.x, c1.y, c1.z, c1.w}; \
            _Pragma("unroll") \
            for (int i = 0; i < 8; ++i) { \
                _Float16 hb = (_Float16)xv[i]; \
                axh[i] = hb; \
                axl[i] = (_Float16)(xv[i] - (float)hb); \
            } \
        } else if (lg == 2) { \
            axh[0] = (_Float16)1.0f; \
        } \
        aR0 = __builtin_amdgcn_mfma_f32_16x16x32_f16(axh, Bi[0], Z4, 0, 0, 0); \
        aR1 = __builtin_amdgcn_mfma_f32_16x16x32_f16(axl, Bi[0], Z4, 0, 0, 0); \
        aZ0 = __builtin_amdgcn_mfma_f32_16x16x32_f16(axh, Bi[1], Z4, 0, 0, 0); \
        aZ1 = __builtin_amdgcn_mfma_f32_16x16x32_f16(axl, Bi[1], Z4, 0, 0, 0); \
        aI  = __builtin_amdgcn_mfma_f32_16x16x32_f16(axh, Bi[2], Z4, 0, 0, 0); \
        aI  = __builtin_amdgcn_mfma_f32_16x16x32_f16(axl, Bi[2], aI, 0, 0, 0); \
        aH0 = Z4; aH1 = Z4; \
    } while (0)

    IH_SHADOW(0);

    for (int t = 0; t < TT; ++t) {
        const int rb = t & 1, wb = rb ^ 1;

        #pragma unroll
        for (int kf = 0; kf < 4; ++kf) {
            const int ko = kf * 32 + lg * 8;
            f16x8 ahh = *(const f16x8*)&Hhi[rb][l15][ko];
            f16x8 ahl = *(const f16x8*)&Hlo[rb][l15][ko];
            if ((kf & 1) == 0) {
                aR0 = __builtin_amdgcn_mfma_f32_16x16x32_f16(ahh, Bh[0][kf], aR0, 0, 0, 0);
                aR0 = __builtin_amdgcn_mfma_f32_16x16x32_f16(ahl, Bh[0][kf], aR0, 0, 0, 0);
                aZ0 = __builtin_amdgcn_mfma_f32_16x16x32_f16(ahh, Bh[1][kf], aZ0, 0, 0, 0);
                aZ0 = __builtin_amdgcn_mfma_f32_16x16x32_f16(ahl, Bh[1][kf], aZ0, 0, 0, 0);
                aH0 = __builtin_amdgcn_mfma_f32_16x16x32_f16(ahh, Bh[2][kf], aH0, 0, 0, 0);
                aH0 = __builtin_amdgcn_mfma_f32_16x16x32_f16(ahl, Bh[2][kf], aH0, 0, 0, 0);
            } else {
                aR1 = __builtin_amdgcn_mfma_f32_16x16x32_f16(ahh, Bh[0][kf], aR1, 0, 0, 0);
                aR1 = __builtin_amdgcn_mfma_f32_16x16x32_f16(ahl, Bh[0][kf], aR1, 0, 0, 0);
                aZ1 = __builtin_amdgcn_mfma_f32_16x16x32_f16(ahh, Bh[1][kf], aZ1, 0, 0, 0);
                aZ1 = __builtin_amdgcn_mfma_f32_16x16x32_f16(ahl, Bh[1][kf], aZ1, 0, 0, 0);
                aH1 = __builtin_amdgcn_mfma_f32_16x16x32_f16(ahh, Bh[2][kf], aH1, 0, 0, 0);
                aH1 = __builtin_amdgcn_mfma_f32_16x16x32_f16(ahl, Bh[2][kf], aH1, 0, 0, 0);
            }
        }

        f32x4 aR = aR0 + aR1;
        f32x4 aZ = aZ0 + aZ1;
        f32x4 aH = aH0 + aH1;
        f32x4 aIv = aI;

        if (lg < 2) {
            #pragma unroll
            for (int p = 0; p < 4; ++p) {
                float r = __builtin_amdgcn_rcpf(1.0f + __expf(-aR[p]));
                float z = __builtin_amdgcn_rcpf(1.0f + __expf(-aZ[p]));
                float pre = fmaf(r, aH[p] + bhn, aIv[p]);
                float e2 = __expf(2.0f * pre);
                float n = fmaf(-2.0f, __builtin_amdgcn_rcpf(e2 + 1.0f), 1.0f);
                float h = fmaf(z, hprev[p] - n, n);
                hprev[p] = h;
                _Float16 hb = (_Float16)h;
                _Float16 lb = (_Float16)(h - (float)hb);
                const int seq = lg * 4 + p;
                Hhi[wb][seq][u] = *(unsigned short*)&hb;
                Hlo[wb][seq][u] = *(unsigned short*)&lb;
            }
        }

        if (t + 1 < TT) IH_SHADOW(t + 1);
        __syncthreads();
    }
#undef IH_SHADOW

    if (lg < 2) {
        #pragma unroll
        for (int p = 0; p < 4; ++p)
            temporal[(size_t)(m0 + lg * 4 + p) * HH + u] = hprev[p];
    }
}

// ---------------- fused GCN layer: gather + linear + LayerNorm + ReLU ----------------
__global__ __launch_bounds__(256) void gcn_kernel(
    const float* __restrict__ xin,     // [BB][NN][HH]
    const int* __restrict__ rowptr,    // [NN+1]
    const int* __restrict__ esrc,      // edges sorted by dst
    const float* __restrict__ enorm,
    const float* __restrict__ Wt,      // [HH][HH]  Wt[k][j] = W[j][k]
    const float* __restrict__ bias,
    const float* __restrict__ gma, const float* __restrict__ bta,
    float* __restrict__ out)           // [BB][NN][HH]
{
    const int n = blockIdx.x;
    const int tid = threadIdx.x;
    const int j = tid & 127;
    const int half = tid >> 7;
    const int beg = rowptr[n], end = rowptr[n + 1];
    const int len = end - beg;
    const int mid = beg + ((len + 1) >> 1);
    int e        = half ? mid : beg;
    const int e1 = half ? end : mid;

    float a0 = 0.f, a1 = 0.f, a2 = 0.f, a3 = 0.f;
    for (; e + 1 < e1; e += 2) {
        int   s0 = esrc[e],   s1 = esrc[e + 1];
        float m0 = enorm[e],  m1 = enorm[e + 1];
        const float* p0 = xin + (size_t)s0 * HH + j;
        const float* p1 = xin + (size_t)s1 * HH + j;
        float v00 = p0[0], v01 = p0[NN*HH], v02 = p0[2*NN*HH], v03 = p0[3*NN*HH];
        float v10 = p1[0], v11 = p1[NN*HH], v12 = p1[2*NN*HH], v13 = p1[3*NN*HH];
        a0 = fmaf(m0, v00, a0); a1 = fmaf(m0, v01, a1);
        a2 = fmaf(m0, v02, a2); a3 = fmaf(m0, v03, a3);
        a0 = fmaf(m1, v10, a0); a1 = fmaf(m1, v11, a1);
        a2 = fmaf(m1, v12, a2); a3 = fmaf(m1, v13, a3);
    }
    if (e < e1) {
        int s0 = esrc[e]; float m0 = enorm[e];
        const float* p0 = xin + (size_t)s0 * HH + j;
        a0 = fmaf(m0, p0[0],       a0); a1 = fmaf(m0, p0[NN*HH],   a1);
        a2 = fmaf(m0, p0[2*NN*HH], a2); a3 = fmaf(m0, p0[3*NN*HH], a3);
    }

    __shared__ __align__(16) float agg[BB][HH];
    __shared__ __align__(16) float pagg[BB][HH];
    if (half) {
        pagg[0][j] = a0; pagg[1][j] = a1; pagg[2][j] = a2; pagg[3][j] = a3;
    }
    __syncthreads();
    if (!half) {
        agg[0][j] = a0 + pagg[0][j]; agg[1][j] = a1 + pagg[1][j];
        agg[2][j] = a2 + pagg[2][j]; agg[3][j] = a3 + pagg[3][j];
    }
    __syncthreads();

    const float bj = bias[j];
    const int b0 = half * 2, b1 = half * 2 + 1;
    float c0 = bj, c1 = bj;
    #pragma unroll 4
    for (int k = 0; k < HH; ++k) {
        float wv = Wt[k * HH + j];
        c0 = fmaf(wv, agg[b0][k], c0);
        c1 = fmaf(wv, agg[b1][k], c1);
    }

    const int lane = tid & 63, wv_ = (tid >> 6) & 1;
    __shared__ float red[2][2][2][2];   // [half][wave][q][{s1,s2}]
    {
        float s1 = c0, s2 = c0 * c0;
        for (int off = 32; off >= 1; off >>= 1) { s1 += __shfl_down(s1, off); s2 += __shfl_down(s2, off); }
        if (lane == 0) { red[half][wv_][0][0] = s1; red[half][wv_][0][1] = s2; }
        s1 = c1; s2 = c1 * c1;
        for (int off = 32; off >= 1; off >>= 1) { s1 += __shfl_down(s1, off); s2 += __shfl_down(s2, off); }
        if (lane == 0) { red[half][wv_][1][0] = s1; red[half][wv_][1][1] = s2; }
    }
    __syncthreads();

    const float gj = gma[j], btj = bta[j];
    #pragma unroll
    for (int q = 0; q < 2; ++q) {
        float cv = q ? c1 : c0;
        float s1 = red[half][0][q][0] + red[half][1][q][0];
        float s2 = red[half][0][q][1] + red[half][1][q][1];
        float mu = s1 * (1.0f / HH);
        float var = s2 * (1.0f / HH) - mu * mu;
        float y = (cv - mu) * rsqrtf(var + 1e-5f) * gj + btj;
        out[((size_t)(half * 2 + q) * NN + n) * HH + j] = fmaxf(y, 0.0f);
    }
}

// ---------------- classifier (fused 2-layer MLP) ----------------
__global__ __launch_bounds__(128) void classifier_kernel(
    const float* __restrict__ tin,   // temporal [BN][HH]
    const float* __restrict__ sin_,  // spatial  [BN][HH]
    const float* __restrict__ Wt1,   // [2*HH][HH]
    const float* __restrict__ b1,
    const float* __restrict__ W2,    // [CC][HH]
    const float* __restrict__ b2,
    float* __restrict__ out)         // [BN][CC]
{
    const int j = threadIdx.x;
    const int r0 = blockIdx.x * 8;
    __shared__ __align__(16) float tb[HH][8];
    __shared__ __align__(16) float sb[HH][8];
    __shared__ __align__(16) float h1[HH][8];
    for (int i = j; i < 8 * HH; i += 128) {
        int r = i >> 7, k = i & 127;
        tb[k][r] = tin [(size_t)(r0 + r) * HH + k];
        sb[k][r] = sin_[(size_t)(r0 + r) * HH + k];
    }
    __syncthreads();

    float acc[8];
    float bj = b1[j];
    #pragma unroll
    for (int r = 0; r < 8; ++r) acc[r] = bj;
    #pragma unroll 2
    for (int k = 0; k < HH; ++k) {
        float w = Wt1[k * HH + j];
        float4 a  = *(const float4*)&tb[k][0];
        float4 b4 = *(const float4*)&tb[k][4];
        acc[0] = fmaf(w, a.x,  acc[0]); acc[1] = fmaf(w, a.y,  acc[1]);
        acc[2] = fmaf(w, a.z,  acc[2]); acc[3] = fmaf(w, a.w,  acc[3]);
        acc[4] = fmaf(w, b4.x, acc[4]); acc[5] = fmaf(w, b4.y, acc[5]);
        acc[6] = fmaf(w, b4.z, acc[6]); acc[7] = fmaf(w, b4.w, acc[7]);
    }
    #pragma unroll 2
    for (int k = 0; k < HH; ++k) {
        float w = Wt1[(HH + k) * HH + j];
        float4 a  = *(const float4*)&sb[k][0];
        float4 b4 = *(const float4*)&sb[k][4];
        acc[0] = fmaf(w, a.x,  acc[0]); acc[1] = fmaf(w, a.y,  acc[1]);
        acc[2] = fmaf(w, a.z,  acc[2]); acc[3] = fmaf(w, a.w,  acc[3]);
        acc[4] = fmaf(w, b4.x, acc[4]); acc[5] = fmaf(w, b4.y, acc[5]);
        acc[6] = fmaf(w, b4.z, acc[6]); acc[7] = fmaf(w, b4.w, acc[7]);
    }
    #pragma unroll
    for (int r = 0; r < 8; ++r) h1[j][r] = fmaxf(acc[r], 0.0f);
    __syncthreads();

    if (j < 8 * CC) {
        int r = j / CC, c = j - r * CC;
        float a = b2[c];
        for (int k = 0; k < HH; ++k) a = fmaf(W2[c * HH + k], h1[k][r], a);
        out[(size_t)(r0 + r) * CC + c] = a;
    }
}

// ---------------- launch ----------------
extern "C" void kernel_launch(void* const* d_in, const int* in_sizes, int n_in,
                              void* d_out, int out_size, void* d_ws, size_t ws_size,
                              hipStream_t stream) {
    const float* x    = (const float*)d_in[0];
    const int*   ei   = (const int*)  d_in[1];
    const float* W_ih = (const float*)d_in[2];
    const float* W_hh = (const float*)d_in[3];
    const float* b_ih = (const float*)d_in[4];
    const float* b_hh = (const float*)d_in[5];
    const float* gW1  = (const float*)d_in[6];
    const float* gb1  = (const float*)d_in[7];
    const float* gW2  = (const float*)d_in[8];
    const float* gb2  = (const float*)d_in[9];
    const float* lg1  = (const float*)d_in[10];
    const float* lb1  = (const float*)d_in[11];
    const float* lg2  = (const float*)d_in[12];
    const float* lb2  = (const float*)d_in[13];
    const float* cW1  = (const float*)d_in[14];
    const float* cb1  = (const float*)d_in[15];
    const float* cW2  = (const float*)d_in[16];
    const float* cb2  = (const float*)d_in[17];
    float* out = (float*)d_out;

    float* ws = (float*)d_ws;
    float* Wt_g1 = ws;  ws += 128 * 128;
    float* Wt_g2 = ws;  ws += 128 * 128;
    float* Wt_c1 = ws;  ws += 256 * 128;
    float* dis   = ws;  ws += 2048;
    float* enorm = ws;  ws += EE;
    float* temporal = ws; ws += (size_t)BN * HH;
    float* sA    = ws;  ws += (size_t)BN * HH;
    float* sB    = ws;  ws += (size_t)BN * HH;
    int* ip      = (int*)ws;
    int* rowptr  = ip;  ip += 2080;
    int* cursor  = ip;  ip += 2048;
    int* esrc    = ip;  ip += EE;

    const int* srcp = ei;
    const int* dstp = ei + EE;

    prep_kernel<<<257, 256, 0, stream>>>(dstp, rowptr, cursor, dis,
                                         gW1, gW2, cW1, Wt_g1, Wt_g2, Wt_c1);

    gru_csr_kernel<<<GRUB + EE / 512, 512, 0, stream>>>(
        x, W_hh, W_ih, b_ih, b_hh, temporal,
        srcp, dstp, dis, cursor, esrc, enorm);

    gcn_kernel<<<NN, 256, 0, stream>>>(temporal, rowptr, esrc, enorm, Wt_g1, gb1, lg1, lb1, sA);
    gcn_kernel<<<NN, 256, 0, stream>>>(sA, rowptr, esrc, enorm, Wt_g2, gb2, lg2, lb2, sB);

    classifier_kernel<<<BN / 8, 128, 0, stream>>>(temporal, sB, Wt_c1, cb1, cW2, cb2, out);
}

// Round 11
// 180.948 us; speedup vs baseline: 1.6699x; 1.6699x over previous
//
#include <hip/hip_runtime.h>
#include <math.h>

#define BB  4
#define NN  2000
#define TT  24
#define FIN 16
#define HH  128
#define EE  64000
#define CC  6
#define BN  (BB*NN)   // 8000

typedef _Float16 f16x8 __attribute__((ext_vector_type(8)));
typedef float f32x4 __attribute__((ext_vector_type(4)));

// ---------------- prep: [block 0] degree-hist + scan + dis | [1..256] transposes ----
__global__ __launch_bounds__(256) void prep_kernel(
    const int* __restrict__ dst,
    int* __restrict__ rowptr, int* __restrict__ cursor, float* __restrict__ dis,
    const float* __restrict__ gW1, const float* __restrict__ gW2,
    const float* __restrict__ cW1,
    float* __restrict__ o1, float* __restrict__ o2, float* __restrict__ o3)
{
    const int b = blockIdx.x;
    const int tid = threadIdx.x;
    if (b == 0) {
        __shared__ int hist[2048];
        __shared__ int part[256];
        for (int i = tid; i < 2048; i += 256) hist[i] = 0;
        __syncthreads();
        for (int i = tid; i < EE; i += 256) atomicAdd(&hist[dst[i]], 1);
        __syncthreads();
        int base = tid * 8;
        int loc[8]; int s = 0;
        #pragma unroll
        for (int u = 0; u < 8; ++u) { int v = hist[base + u]; loc[u] = s; s += v; }
        part[tid] = s;
        __syncthreads();
        #pragma unroll
        for (int off = 1; off < 256; off <<= 1) {
            int add = (tid >= off) ? part[tid - off] : 0;
            __syncthreads();
            part[tid] += add;
            __syncthreads();
        }
        int offset = (tid > 0) ? part[tid - 1] : 0;
        #pragma unroll
        for (int u = 0; u < 8; ++u) {
            int idx = base + u;
            if (idx < NN) {
                rowptr[idx] = offset + loc[u];
                cursor[idx] = offset + loc[u];
                dis[idx] = rsqrtf(fmaxf((float)hist[idx], 1.0f));
            }
        }
        if (tid == 255) rowptr[NN] = part[255];
    } else if (b <= 64) {
        int idx = (b - 1) * 256 + tid;            // gW1 128x128
        int r = idx >> 7, c = idx & 127;
        o1[c * 128 + r] = gW1[idx];
    } else if (b <= 128) {
        int idx = (b - 65) * 256 + tid;           // gW2 128x128
        int r = idx >> 7, c = idx & 127;
        o2[c * 128 + r] = gW2[idx];
    } else {
        int idx = (b - 129) * 256 + tid;          // cW1 128x256 (128 blocks)
        int r = idx >> 8, c = idx & 255;
        o3[c * 128 + r] = cW1[idx];
    }
}

// ---------------- GRU via MFMA + co-launched csr_fill ----------------
// R9 refuted "more blocks": 1000x8seq doubled MFMA stream -> 2x time, occupancy flat.
// Model: per-step time tracks MFMA instruction count; ~2 blocks/CU co-schedule.
// R10: back to 500 blocks x 16 seqs (proven 69us) and HALVE the MFMA stream:
// drop A-side lo terms (x, h single fp16). fp32 hprev carry stays in registers, so
// fp16-H error does NOT compound through z*h_old - only through W*h (contractive).
// 15 MFMAs/step (12 hh + 3 ih) vs 30. Blocks >= 500 do csr_fill.
// NO launch_bounds min-occupancy arg (R2/R3: forced VGPR caps -> GB-scale spill).
#define HP2 136
#define GRUB 500

__global__ __launch_bounds__(512) void gru_csr_kernel(
    const float* __restrict__ x,       // [BN][TT][FIN]
    const float* __restrict__ W_hh,    // [384][128]
    const float* __restrict__ W_ih,    // [384][16]
    const float* __restrict__ b_ih, const float* __restrict__ b_hh,
    float* __restrict__ temporal,      // [BN][HH]
    const int* __restrict__ src, const int* __restrict__ dst,
    const float* __restrict__ dis, int* __restrict__ cursor,
    int* __restrict__ esrc, float* __restrict__ enorm)
{
    const int tid  = threadIdx.x;

    if (blockIdx.x >= GRUB) {   // ---- csr_fill part (125 blocks x 512 = 64000) ----
        int e = (blockIdx.x - GRUB) * 512 + tid;
        if (e < EE) {
            int d = dst[e], s = src[e];
            int pos = atomicAdd(&cursor[d], 1);
            esrc[pos] = s;
            enorm[pos] = dis[s] * dis[d];
        }
        return;
    }

    const int lane = tid & 63;
    const int w    = tid >> 6;
    const int l15  = lane & 15;
    const int lg   = lane >> 4;
    const int m0   = blockIdx.x * 16;
    const int u    = w * 16 + l15;

    __shared__ __align__(16) unsigned short Hhi[2][16][HP2];   // 8.5 KB
    __shared__ __align__(16) unsigned short Xhi[TT][16][FIN];  // 12 KB

    // ---- B-fragments: W_hh (fp16 single), 3 gates x 4 kf ----
    f16x8 Bh[3][4];
    #pragma unroll
    for (int g = 0; g < 3; ++g) {
        const int col = g * 128 + u;
        #pragma unroll
        for (int kf = 0; kf < 4; ++kf) {
            const float* wp = W_hh + col * 128 + kf * 32 + lg * 8;
            float4 c0 = *(const float4*)wp;
            float4 c1 = *(const float4*)(wp + 4);
            f16x8 b;
            b[0] = (_Float16)c0.x; b[1] = (_Float16)c0.y;
            b[2] = (_Float16)c0.z; b[3] = (_Float16)c0.w;
            b[4] = (_Float16)c1.x; b[5] = (_Float16)c1.y;
            b[6] = (_Float16)c1.z; b[7] = (_Float16)c1.w;
            Bh[g][kf] = b;
        }
    }
    // ---- B-fragments: W_ih + bias at k==16 ----
    f16x8 Bi[3];
    #pragma unroll
    for (int g = 0; g < 3; ++g) {
        const int col = g * 128 + u;
        f16x8 b;
        #pragma unroll
        for (int i = 0; i < 8; ++i) b[i] = (_Float16)0.0f;
        if (lg < 2) {
            const float* wp = W_ih + col * 16 + lg * 8;
            float4 c0 = *(const float4*)wp;
            float4 c1 = *(const float4*)(wp + 4);
            b[0] = (_Float16)c0.x; b[1] = (_Float16)c0.y;
            b[2] = (_Float16)c0.z; b[3] = (_Float16)c0.w;
            b[4] = (_Float16)c1.x; b[5] = (_Float16)c1.y;
            b[6] = (_Float16)c1.z; b[7] = (_Float16)c1.w;
        } else if (lg == 2) {
            float bias = b_ih[col] + ((g < 2) ? b_hh[col] : 0.0f);
            b[0] = (_Float16)bias;   // k == 16
        }
        Bi[g] = b;
    }

    const float bhn = b_hh[256 + u];
    float hprev[4] = {0.0f, 0.0f, 0.0f, 0.0f};

    // ---- stage X once: fp32 -> fp16 (hi only), [t][seq][f] ----
    for (int i = tid; i < TT * 16 * FIN; i += 512) {
        int t   = i >> 8;
        int rem = i & 255;
        int seq = rem >> 4;
        int f   = rem & 15;
        float v = x[(size_t)(m0 + seq) * (TT * FIN) + t * FIN + f];
        _Float16 hb = (_Float16)v;
        Xhi[t][seq][f] = *(unsigned short*)&hb;
    }
    for (int i = tid; i < 16 * HP2; i += 512) (&Hhi[0][0][0])[i] = 0;
    __syncthreads();

    const f32x4 Z4 = (f32x4){0.f, 0.f, 0.f, 0.f};
    f32x4 aR, aZ, aH, aI;

    // ih for step tt into fresh accumulators (runs in barrier shadow for tt>0)
#define IH_SHADOW(tt) do { \
        f16x8 axh; \
        _Float16 zz = (_Float16)0.0f; \
        axh = (f16x8){zz,zz,zz,zz,zz,zz,zz,zz}; \
        if (lg < 2) { \
            axh = *(const f16x8*)&Xhi[tt][l15][lg * 8]; \
        } else if (lg == 2) { \
            axh[0] = (_Float16)1.0f; \
        } \
        aR = __builtin_amdgcn_mfma_f32_16x16x32_f16(axh, Bi[0], Z4, 0, 0, 0); \
        aZ = __builtin_amdgcn_mfma_f32_16x16x32_f16(axh, Bi[1], Z4, 0, 0, 0); \
        aI = __builtin_amdgcn_mfma_f32_16x16x32_f16(axh, Bi[2], Z4, 0, 0, 0); \
        aH = Z4; \
    } while (0)

    IH_SHADOW(0);

    for (int t = 0; t < TT; ++t) {
        const int rb = t & 1, wb = rb ^ 1;

        #pragma unroll
        for (int kf = 0; kf < 4; ++kf) {
            const int ko = kf * 32 + lg * 8;
            f16x8 ahh = *(const f16x8*)&Hhi[rb][l15][ko];
            aR = __builtin_amdgcn_mfma_f32_16x16x32_f16(ahh, Bh[0][kf], aR, 0, 0, 0);
            aZ = __builtin_amdgcn_mfma_f32_16x16x32_f16(ahh, Bh[1][kf], aZ, 0, 0, 0);
            aH = __builtin_amdgcn_mfma_f32_16x16x32_f16(ahh, Bh[2][kf], aH, 0, 0, 0);
        }

        f32x4 aRv = aR, aZv = aZ, aHv = aH, aIv = aI;

        #pragma unroll
        for (int p = 0; p < 4; ++p) {
            float r = __builtin_amdgcn_rcpf(1.0f + __expf(-aRv[p]));
            float z = __builtin_amdgcn_rcpf(1.0f + __expf(-aZv[p]));
            float pre = fmaf(r, aHv[p] + bhn, aIv[p]);
            float e2 = __expf(2.0f * pre);
            float n = fmaf(-2.0f, __builtin_amdgcn_rcpf(e2 + 1.0f), 1.0f);
            float h = fmaf(z, hprev[p] - n, n);
            hprev[p] = h;                       // fp32 carry stays in registers
            _Float16 hb = (_Float16)h;
            const int seq = lg * 4 + p;
            Hhi[wb][seq][u] = *(unsigned short*)&hb;
        }

        if (t + 1 < TT) IH_SHADOW(t + 1);
        __syncthreads();
    }
#undef IH_SHADOW

    #pragma unroll
    for (int p = 0; p < 4; ++p)
        temporal[(size_t)(m0 + lg * 4 + p) * HH + u] = hprev[p];
}

// ---------------- GCN layer 1: gather + linear + LayerNorm + ReLU ----------------
__global__ __launch_bounds__(256) void gcn_kernel(
    const float* __restrict__ xin,     // [BB][NN][HH]
    const int* __restrict__ rowptr,
    const int* __restrict__ esrc,
    const float* __restrict__ enorm,
    const float* __restrict__ Wt,      // [HH][HH]  Wt[k][j] = W[j][k]
    const float* __restrict__ bias,
    const float* __restrict__ gma, const float* __restrict__ bta,
    float* __restrict__ out)           // [BB][NN][HH]
{
    const int n = blockIdx.x;
    const int tid = threadIdx.x;
    const int j = tid & 127;
    const int half = tid >> 7;
    const int beg = rowptr[n], end = rowptr[n + 1];
    const int len = end - beg;
    const int mid = beg + ((len + 1) >> 1);
    int e        = half ? mid : beg;
    const int e1 = half ? end : mid;

    float a0 = 0.f, a1 = 0.f, a2 = 0.f, a3 = 0.f;
    for (; e + 1 < e1; e += 2) {
        int   s0 = esrc[e],   s1 = esrc[e + 1];
        float m0 = enorm[e],  m1 = enorm[e + 1];
        const float* p0 = xin + (size_t)s0 * HH + j;
        const float* p1 = xin + (size_t)s1 * HH + j;
        float v00 = p0[0], v01 = p0[NN*HH], v02 = p0[2*NN*HH], v03 = p0[3*NN*HH];
        float v10 = p1[0], v11 = p1[NN*HH], v12 = p1[2*NN*HH], v13 = p1[3*NN*HH];
        a0 = fmaf(m0, v00, a0); a1 = fmaf(m0, v01, a1);
        a2 = fmaf(m0, v02, a2); a3 = fmaf(m0, v03, a3);
        a0 = fmaf(m1, v10, a0); a1 = fmaf(m1, v11, a1);
        a2 = fmaf(m1, v12, a2); a3 = fmaf(m1, v13, a3);
    }
    if (e < e1) {
        int s0 = esrc[e]; float m0 = enorm[e];
        const float* p0 = xin + (size_t)s0 * HH + j;
        a0 = fmaf(m0, p0[0],       a0); a1 = fmaf(m0, p0[NN*HH],   a1);
        a2 = fmaf(m0, p0[2*NN*HH], a2); a3 = fmaf(m0, p0[3*NN*HH], a3);
    }

    __shared__ __align__(16) float agg[BB][HH];
    __shared__ __align__(16) float pagg[BB][HH];
    if (half) {
        pagg[0][j] = a0; pagg[1][j] = a1; pagg[2][j] = a2; pagg[3][j] = a3;
    }
    __syncthreads();
    if (!half) {
        agg[0][j] = a0 + pagg[0][j]; agg[1][j] = a1 + pagg[1][j];
        agg[2][j] = a2 + pagg[2][j]; agg[3][j] = a3 + pagg[3][j];
    }
    __syncthreads();

    const float bj = bias[j];
    const int b0 = half * 2, b1 = half * 2 + 1;
    float c0 = bj, c1 = bj;
    #pragma unroll 4
    for (int k = 0; k < HH; ++k) {
        float wv = Wt[k * HH + j];
        c0 = fmaf(wv, agg[b0][k], c0);
        c1 = fmaf(wv, agg[b1][k], c1);
    }

    const int lane = tid & 63, wv_ = (tid >> 6) & 1;
    __shared__ float red[2][2][2][2];
    {
        float s1 = c0, s2 = c0 * c0;
        for (int off = 32; off >= 1; off >>= 1) { s1 += __shfl_down(s1, off); s2 += __shfl_down(s2, off); }
        if (lane == 0) { red[half][wv_][0][0] = s1; red[half][wv_][0][1] = s2; }
        s1 = c1; s2 = c1 * c1;
        for (int off = 32; off >= 1; off >>= 1) { s1 += __shfl_down(s1, off); s2 += __shfl_down(s2, off); }
        if (lane == 0) { red[half][wv_][1][0] = s1; red[half][wv_][1][1] = s2; }
    }
    __syncthreads();

    const float gj = gma[j], btj = bta[j];
    #pragma unroll
    for (int q = 0; q < 2; ++q) {
        float cv = q ? c1 : c0;
        float s1 = red[half][0][q][0] + red[half][1][q][0];
        float s2 = red[half][0][q][1] + red[half][1][q][1];
        float mu = s1 * (1.0f / HH);
        float var = s2 * (1.0f / HH) - mu * mu;
        float y = (cv - mu) * rsqrtf(var + 1e-5f) * gj + btj;
        out[((size_t)(half * 2 + q) * NN + n) * HH + j] = fmaxf(y, 0.0f);
    }
}

// ---------------- GCN layer 2 + fused classifier ----------------
// Same gather/GEMV/LN as gcn_kernel, but the ReLU'd spatial output stays in LDS and
// the classifier (row-local in (b,n)) runs in the epilogue: kills one 1000-block
// launch and the 8MB sB write+read round trip.
__global__ __launch_bounds__(256) void gcn2_cls_kernel(
    const float* __restrict__ xin,     // sA [BB][NN][HH]
    const int* __restrict__ rowptr,
    const int* __restrict__ esrc,
    const float* __restrict__ enorm,
    const float* __restrict__ Wt,      // Wt_g2
    const float* __restrict__ bias,
    const float* __restrict__ gma, const float* __restrict__ bta,
    const float* __restrict__ temporal,// [BB*NN][HH]
    const float* __restrict__ Wt1,     // Wt_c1 [256][128]
    const float* __restrict__ b1,
    const float* __restrict__ W2,      // [CC][HH]
    const float* __restrict__ b2,
    float* __restrict__ out)           // [BB][NN][CC]
{
    const int n = blockIdx.x;
    const int tid = threadIdx.x;
    const int j = tid & 127;
    const int half = tid >> 7;

    __shared__ __align__(16) float t_[BB][HH];   // temporal rows (loaded early)
    for (int i = tid; i < BB * HH; i += 256) {
        int b = i >> 7, k = i & 127;
        t_[b][k] = temporal[((size_t)b * NN + n) * HH + k];
    }

    const int beg = rowptr[n], end = rowptr[n + 1];
    const int len = end - beg;
    const int mid = beg + ((len + 1) >> 1);
    int e        = half ? mid : beg;
    const int e1 = half ? end : mid;

    float a0 = 0.f, a1 = 0.f, a2 = 0.f, a3 = 0.f;
    for (; e + 1 < e1; e += 2) {
        int   s0 = esrc[e],   s1 = esrc[e + 1];
        float m0 = enorm[e],  m1 = enorm[e + 1];
        const float* p0 = xin + (size_t)s0 * HH + j;
        const float* p1 = xin + (size_t)s1 * HH + j;
        float v00 = p0[0], v01 = p0[NN*HH], v02 = p0[2*NN*HH], v03 = p0[3*NN*HH];
        float v10 = p1[0], v11 = p1[NN*HH], v12 = p1[2*NN*HH], v13 = p1[3*NN*HH];
        a0 = fmaf(m0, v00, a0); a1 = fmaf(m0, v01, a1);
        a2 = fmaf(m0, v02, a2); a3 = fmaf(m0, v03, a3);
        a0 = fmaf(m1, v10, a0); a1 = fmaf(m1, v11, a1);
        a2 = fmaf(m1, v12, a2); a3 = fmaf(m1, v13, a3);
    }
    if (e < e1) {
        int s0 = esrc[e]; float m0 = enorm[e];
        const float* p0 = xin + (size_t)s0 * HH + j;
        a0 = fmaf(m0, p0[0],       a0); a1 = fmaf(m0, p0[NN*HH],   a1);
        a2 = fmaf(m0, p0[2*NN*HH], a2); a3 = fmaf(m0, p0[3*NN*HH], a3);
    }

    __shared__ __align__(16) float agg[BB][HH];
    __shared__ __align__(16) float pagg[BB][HH];
    if (half) {
        pagg[0][j] = a0; pagg[1][j] = a1; pagg[2][j] = a2; pagg[3][j] = a3;
    }
    __syncthreads();
    if (!half) {
        agg[0][j] = a0 + pagg[0][j]; agg[1][j] = a1 + pagg[1][j];
        agg[2][j] = a2 + pagg[2][j]; agg[3][j] = a3 + pagg[3][j];
    }
    __syncthreads();

    const float bj = bias[j];
    const int b0 = half * 2, b1q = half * 2 + 1;
    float c0 = bj, c1 = bj;
    #pragma unroll 4
    for (int k = 0; k < HH; ++k) {
        float wv = Wt[k * HH + j];
        c0 = fmaf(wv, agg[b0][k], c0);
        c1 = fmaf(wv, agg[b1q][k], c1);
    }

    const int lane = tid & 63, wv_ = (tid >> 6) & 1;
    __shared__ float red[2][2][2][2];
    {
        float s1 = c0, s2 = c0 * c0;
        for (int off = 32; off >= 1; off >>= 1) { s1 += __shfl_down(s1, off); s2 += __shfl_down(s2, off); }
        if (lane == 0) { red[half][wv_][0][0] = s1; red[half][wv_][0][1] = s2; }
        s1 = c1; s2 = c1 * c1;
        for (int off = 32; off >= 1; off >>= 1) { s1 += __shfl_down(s1, off); s2 += __shfl_down(s2, off); }
        if (lane == 0) { red[half][wv_][1][0] = s1; red[half][wv_][1][1] = s2; }
    }
    __syncthreads();

    __shared__ __align__(16) float s_[BB][HH];   // spatial (LN+ReLU), stays in LDS
    const float gj = gma[j], btj = bta[j];
    #pragma unroll
    for (int q = 0; q < 2; ++q) {
        float cv = q ? c1 : c0;
        float s1 = red[half][0][q][0] + red[half][1][q][0];
        float s2 = red[half][0][q][1] + red[half][1][q][1];
        float mu = s1 * (1.0f / HH);
        float var = s2 * (1.0f / HH) - mu * mu;
        float y = (cv - mu) * rsqrtf(var + 1e-5f) * gj + btj;
        s_[half * 2 + q][j] = fmaxf(y, 0.0f);
    }
    __syncthreads();

    // ---- classifier layer 1: h1[b][j] for b = b0, b1q ----
    __shared__ __align__(16) float h1_[BB][HH];
    float h0a = b1[j], h1a = b1[j];
    #pragma unroll 4
    for (int k = 0; k < HH; ++k) {
        float wv = Wt1[k * HH + j];
        h0a = fmaf(wv, t_[b0][k],  h0a);
        h1a = fmaf(wv, t_[b1q][k], h1a);
    }
    #pragma unroll 4
    for (int k = 0; k < HH; ++k) {
        float wv = Wt1[(HH + k) * HH + j];
        h0a = fmaf(wv, s_[b0][k],  h0a);
        h1a = fmaf(wv, s_[b1q][k], h1a);
    }
    h1_[b0][j]  = fmaxf(h0a, 0.0f);
    h1_[b1q][j] = fmaxf(h1a, 0.0f);
    __syncthreads();

    // ---- classifier layer 2: 24 logits (4 batches x 6 classes) ----
    if (tid < BB * CC) {
        int b = tid / CC, c = tid - b * CC;
        float a = b2[c];
        #pragma unroll 4
        for (int k = 0; k < HH; ++k) a = fmaf(W2[c * HH + k], h1_[b][k], a);
        out[((size_t)b * NN + n) * CC + c] = a;
    }
}

// ---------------- launch ----------------
extern "C" void kernel_launch(void* const* d_in, const int* in_sizes, int n_in,
                              void* d_out, int out_size, void* d_ws, size_t ws_size,
                              hipStream_t stream) {
    const float* x    = (const float*)d_in[0];
    const int*   ei   = (const int*)  d_in[1];
    const float* W_ih = (const float*)d_in[2];
    const float* W_hh = (const float*)d_in[3];
    const float* b_ih = (const float*)d_in[4];
    const float* b_hh = (const float*)d_in[5];
    const float* gW1  = (const float*)d_in[6];
    const float* gb1  = (const float*)d_in[7];
    const float* gW2  = (const float*)d_in[8];
    const float* gb2  = (const float*)d_in[9];
    const float* lg1  = (const float*)d_in[10];
    const float* lb1  = (const float*)d_in[11];
    const float* lg2  = (const float*)d_in[12];
    const float* lb2  = (const float*)d_in[13];
    const float* cW1  = (const float*)d_in[14];
    const float* cb1  = (const float*)d_in[15];
    const float* cW2  = (const float*)d_in[16];
    const float* cb2  = (const float*)d_in[17];
    float* out = (float*)d_out;

    float* ws = (float*)d_ws;
    float* Wt_g1 = ws;  ws += 128 * 128;
    float* Wt_g2 = ws;  ws += 128 * 128;
    float* Wt_c1 = ws;  ws += 256 * 128;
    float* dis   = ws;  ws += 2048;
    float* enorm = ws;  ws += EE;
    float* temporal = ws; ws += (size_t)BN * HH;
    float* sA    = ws;  ws += (size_t)BN * HH;
    int* ip      = (int*)ws;
    int* rowptr  = ip;  ip += 2080;
    int* cursor  = ip;  ip += 2048;
    int* esrc    = ip;  ip += EE;

    const int* srcp = ei;
    const int* dstp = ei + EE;

    prep_kernel<<<257, 256, 0, stream>>>(dstp, rowptr, cursor, dis,
                                         gW1, gW2, cW1, Wt_g1, Wt_g2, Wt_c1);

    gru_csr_kernel<<<GRUB + EE / 512, 512, 0, stream>>>(
        x, W_hh, W_ih, b_ih, b_hh, temporal,
        srcp, dstp, dis, cursor, esrc, enorm);

    gcn_kernel<<<NN, 256, 0, stream>>>(temporal, rowptr, esrc, enorm,
                                       Wt_g1, gb1, lg1, lb1, sA);

    gcn2_cls_kernel<<<NN, 256, 0, stream>>>(sA, rowptr, esrc, enorm,
                                            Wt_g2, gb2, lg2, lb2,
                                            temporal, Wt_c1, cb1, cW2, cb2, out);
}

// Round 12
// 135.826 us; speedup vs baseline: 2.2246x; 1.3322x over previous
//
#include <hip/hip_runtime.h>
#include <math.h>

#define BB  4
#define NN  2000
#define TT  24
#define FIN 16
#define HH  128
#define EE  64000
#define CC  6
#define BN  (BB*NN)   // 8000

typedef _Float16 f16x8 __attribute__((ext_vector_type(8)));
typedef float f32x4 __attribute__((ext_vector_type(4)));

// ---------------- prep: [0..249] edge histogram (global atomics) | [250..505] transposes
// R11 lesson: single-block histogram = 250 serial latency-bound iterations (~70-100us,
// VALUBusy 0.02%). Parallel 250-block version (R2-R7 cnt_kernel) never hit a top-5.
__global__ __launch_bounds__(256) void prep_kernel(
    const int* __restrict__ dst, int* __restrict__ cnt,
    const float* __restrict__ gW1, const float* __restrict__ gW2,
    const float* __restrict__ cW1,
    float* __restrict__ o1, float* __restrict__ o2, float* __restrict__ o3)
{
    const int b = blockIdx.x;
    const int tid = threadIdx.x;
    if (b < 250) {
        int e = b * 256 + tid;            // 250*256 = 64000 = EE exactly
        atomicAdd(&cnt[dst[e]], 1);
    } else if (b < 314) {
        int idx = (b - 250) * 256 + tid;  // gW1 128x128
        int r = idx >> 7, c = idx & 127;
        o1[c * 128 + r] = gW1[idx];
    } else if (b < 378) {
        int idx = (b - 314) * 256 + tid;  // gW2 128x128
        int r = idx >> 7, c = idx & 127;
        o2[c * 128 + r] = gW2[idx];
    } else {
        int idx = (b - 378) * 256 + tid;  // cW1 128x256 (128 blocks)
        int r = idx >> 8, c = idx & 255;
        o3[c * 128 + r] = cW1[idx];
    }
}

// single small block: scan cnt -> rowptr/cursor, dis = rsqrt(max(deg,1))
__global__ __launch_bounds__(256) void scan_kernel(
    const int* __restrict__ cnt,
    int* __restrict__ rowptr, int* __restrict__ cursor, float* __restrict__ dis)
{
    __shared__ int part[256];
    int tid = threadIdx.x;
    int base = tid * 8;
    int loc[8]; int s = 0;
    #pragma unroll
    for (int u = 0; u < 8; ++u) {
        int v = (base + u < NN) ? cnt[base + u] : 0;
        loc[u] = s; s += v;
    }
    part[tid] = s;
    __syncthreads();
    #pragma unroll
    for (int off = 1; off < 256; off <<= 1) {
        int add = (tid >= off) ? part[tid - off] : 0;
        __syncthreads();
        part[tid] += add;
        __syncthreads();
    }
    int offset = (tid > 0) ? part[tid - 1] : 0;
    #pragma unroll
    for (int u = 0; u < 8; ++u) {
        int idx = base + u;
        if (idx < NN) {
            rowptr[idx] = offset + loc[u];
            cursor[idx] = offset + loc[u];
            dis[idx] = rsqrtf(fmaxf((float)cnt[idx], 1.0f));
        }
    }
    if (tid == 255) rowptr[NN] = part[255];
}

// ---------------- GRU via MFMA + co-launched csr_fill (unchanged from R10) ----------
// 500 blocks x 16 seqs; 15 MFMAs/step (A-side single fp16, fp32 hprev carry in regs).
// Blocks >= 500 do csr_fill. NO launch_bounds min-occupancy arg (R2/R3 spill lesson).
#define HP2 136
#define GRUB 500

__global__ __launch_bounds__(512) void gru_csr_kernel(
    const float* __restrict__ x,       // [BN][TT][FIN]
    const float* __restrict__ W_hh,    // [384][128]
    const float* __restrict__ W_ih,    // [384][16]
    const float* __restrict__ b_ih, const float* __restrict__ b_hh,
    float* __restrict__ temporal,      // [BN][HH]
    const int* __restrict__ src, const int* __restrict__ dst,
    const float* __restrict__ dis, int* __restrict__ cursor,
    int* __restrict__ esrc, float* __restrict__ enorm)
{
    const int tid  = threadIdx.x;

    if (blockIdx.x >= GRUB) {   // ---- csr_fill part (125 blocks x 512 = 64000) ----
        int e = (blockIdx.x - GRUB) * 512 + tid;
        if (e < EE) {
            int d = dst[e], s = src[e];
            int pos = atomicAdd(&cursor[d], 1);
            esrc[pos] = s;
            enorm[pos] = dis[s] * dis[d];
        }
        return;
    }

    const int lane = tid & 63;
    const int w    = tid >> 6;
    const int l15  = lane & 15;
    const int lg   = lane >> 4;
    const int m0   = blockIdx.x * 16;
    const int u    = w * 16 + l15;

    __shared__ __align__(16) unsigned short Hhi[2][16][HP2];   // 8.5 KB
    __shared__ __align__(16) unsigned short Xhi[TT][16][FIN];  // 12 KB

    f16x8 Bh[3][4];
    #pragma unroll
    for (int g = 0; g < 3; ++g) {
        const int col = g * 128 + u;
        #pragma unroll
        for (int kf = 0; kf < 4; ++kf) {
            const float* wp = W_hh + col * 128 + kf * 32 + lg * 8;
            float4 c0 = *(const float4*)wp;
            float4 c1 = *(const float4*)(wp + 4);
            f16x8 b;
            b[0] = (_Float16)c0.x; b[1] = (_Float16)c0.y;
            b[2] = (_Float16)c0.z; b[3] = (_Float16)c0.w;
            b[4] = (_Float16)c1.x; b[5] = (_Float16)c1.y;
            b[6] = (_Float16)c1.z; b[7] = (_Float16)c1.w;
            Bh[g][kf] = b;
        }
    }
    f16x8 Bi[3];
    #pragma unroll
    for (int g = 0; g < 3; ++g) {
        const int col = g * 128 + u;
        f16x8 b;
        #pragma unroll
        for (int i = 0; i < 8; ++i) b[i] = (_Float16)0.0f;
        if (lg < 2) {
            const float* wp = W_ih + col * 16 + lg * 8;
            float4 c0 = *(const float4*)wp;
            float4 c1 = *(const float4*)(wp + 4);
            b[0] = (_Float16)c0.x; b[1] = (_Float16)c0.y;
            b[2] = (_Float16)c0.z; b[3] = (_Float16)c0.w;
            b[4] = (_Float16)c1.x; b[5] = (_Float16)c1.y;
            b[6] = (_Float16)c1.z; b[7] = (_Float16)c1.w;
        } else if (lg == 2) {
            float bias = b_ih[col] + ((g < 2) ? b_hh[col] : 0.0f);
            b[0] = (_Float16)bias;   // k == 16
        }
        Bi[g] = b;
    }

    const float bhn = b_hh[256 + u];
    float hprev[4] = {0.0f, 0.0f, 0.0f, 0.0f};

    for (int i = tid; i < TT * 16 * FIN; i += 512) {
        int t   = i >> 8;
        int rem = i & 255;
        int seq = rem >> 4;
        int f   = rem & 15;
        float v = x[(size_t)(m0 + seq) * (TT * FIN) + t * FIN + f];
        _Float16 hb = (_Float16)v;
        Xhi[t][seq][f] = *(unsigned short*)&hb;
    }
    for (int i = tid; i < 16 * HP2; i += 512) (&Hhi[0][0][0])[i] = 0;
    __syncthreads();

    const f32x4 Z4 = (f32x4){0.f, 0.f, 0.f, 0.f};
    f32x4 aR, aZ, aH, aI;

#define IH_SHADOW(tt) do { \
        f16x8 axh; \
        _Float16 zz = (_Float16)0.0f; \
        axh = (f16x8){zz,zz,zz,zz,zz,zz,zz,zz}; \
        if (lg < 2) { \
            axh = *(const f16x8*)&Xhi[tt][l15][lg * 8]; \
        } else if (lg == 2) { \
            axh[0] = (_Float16)1.0f; \
        } \
        aR = __builtin_amdgcn_mfma_f32_16x16x32_f16(axh, Bi[0], Z4, 0, 0, 0); \
        aZ = __builtin_amdgcn_mfma_f32_16x16x32_f16(axh, Bi[1], Z4, 0, 0, 0); \
        aI = __builtin_amdgcn_mfma_f32_16x16x32_f16(axh, Bi[2], Z4, 0, 0, 0); \
        aH = Z4; \
    } while (0)

    IH_SHADOW(0);

    for (int t = 0; t < TT; ++t) {
        const int rb = t & 1, wb = rb ^ 1;

        #pragma unroll
        for (int kf = 0; kf < 4; ++kf) {
            const int ko = kf * 32 + lg * 8;
            f16x8 ahh = *(const f16x8*)&Hhi[rb][l15][ko];
            aR = __builtin_amdgcn_mfma_f32_16x16x32_f16(ahh, Bh[0][kf], aR, 0, 0, 0);
            aZ = __builtin_amdgcn_mfma_f32_16x16x32_f16(ahh, Bh[1][kf], aZ, 0, 0, 0);
            aH = __builtin_amdgcn_mfma_f32_16x16x32_f16(ahh, Bh[2][kf], aH, 0, 0, 0);
        }

        f32x4 aRv = aR, aZv = aZ, aHv = aH, aIv = aI;

        #pragma unroll
        for (int p = 0; p < 4; ++p) {
            float r = __builtin_amdgcn_rcpf(1.0f + __expf(-aRv[p]));
            float z = __builtin_amdgcn_rcpf(1.0f + __expf(-aZv[p]));
            float pre = fmaf(r, aHv[p] + bhn, aIv[p]);
            float e2 = __expf(2.0f * pre);
            float n = fmaf(-2.0f, __builtin_amdgcn_rcpf(e2 + 1.0f), 1.0f);
            float h = fmaf(z, hprev[p] - n, n);
            hprev[p] = h;
            _Float16 hb = (_Float16)h;
            const int seq = lg * 4 + p;
            Hhi[wb][seq][u] = *(unsigned short*)&hb;
        }

        if (t + 1 < TT) IH_SHADOW(t + 1);
        __syncthreads();
    }
#undef IH_SHADOW

    #pragma unroll
    for (int p = 0; p < 4; ++p)
        temporal[(size_t)(m0 + lg * 4 + p) * HH + u] = hprev[p];
}

// ---------------- GCN layer 1: gather + linear + LayerNorm + ReLU ----------------
__global__ __launch_bounds__(256) void gcn_kernel(
    const float* __restrict__ xin,     // [BB][NN][HH]
    const int* __restrict__ rowptr,
    const int* __restrict__ esrc,
    const float* __restrict__ enorm,
    const float* __restrict__ Wt,      // [HH][HH]
    const float* __restrict__ bias,
    const float* __restrict__ gma, const float* __restrict__ bta,
    float* __restrict__ out)           // [BB][NN][HH]
{
    const int n = blockIdx.x;
    const int tid = threadIdx.x;
    const int j = tid & 127;
    const int half = tid >> 7;
    const int beg = rowptr[n], end = rowptr[n + 1];
    const int len = end - beg;
    const int mid = beg + ((len + 1) >> 1);
    int e        = half ? mid : beg;
    const int e1 = half ? end : mid;

    float a0 = 0.f, a1 = 0.f, a2 = 0.f, a3 = 0.f;
    for (; e + 1 < e1; e += 2) {
        int   s0 = esrc[e],   s1 = esrc[e + 1];
        float m0 = enorm[e],  m1 = enorm[e + 1];
        const float* p0 = xin + (size_t)s0 * HH + j;
        const float* p1 = xin + (size_t)s1 * HH + j;
        float v00 = p0[0], v01 = p0[NN*HH], v02 = p0[2*NN*HH], v03 = p0[3*NN*HH];
        float v10 = p1[0], v11 = p1[NN*HH], v12 = p1[2*NN*HH], v13 = p1[3*NN*HH];
        a0 = fmaf(m0, v00, a0); a1 = fmaf(m0, v01, a1);
        a2 = fmaf(m0, v02, a2); a3 = fmaf(m0, v03, a3);
        a0 = fmaf(m1, v10, a0); a1 = fmaf(m1, v11, a1);
        a2 = fmaf(m1, v12, a2); a3 = fmaf(m1, v13, a3);
    }
    if (e < e1) {
        int s0 = esrc[e]; float m0 = enorm[e];
        const float* p0 = xin + (size_t)s0 * HH + j;
        a0 = fmaf(m0, p0[0],       a0); a1 = fmaf(m0, p0[NN*HH],   a1);
        a2 = fmaf(m0, p0[2*NN*HH], a2); a3 = fmaf(m0, p0[3*NN*HH], a3);
    }

    __shared__ __align__(16) float agg[BB][HH];
    __shared__ __align__(16) float pagg[BB][HH];
    if (half) {
        pagg[0][j] = a0; pagg[1][j] = a1; pagg[2][j] = a2; pagg[3][j] = a3;
    }
    __syncthreads();
    if (!half) {
        agg[0][j] = a0 + pagg[0][j]; agg[1][j] = a1 + pagg[1][j];
        agg[2][j] = a2 + pagg[2][j]; agg[3][j] = a3 + pagg[3][j];
    }
    __syncthreads();

    const float bj = bias[j];
    const int b0 = half * 2, b1 = half * 2 + 1;
    float c0 = bj, c1 = bj;
    #pragma unroll 4
    for (int k = 0; k < HH; ++k) {
        float wv = Wt[k * HH + j];
        c0 = fmaf(wv, agg[b0][k], c0);
        c1 = fmaf(wv, agg[b1][k], c1);
    }

    const int lane = tid & 63, wv_ = (tid >> 6) & 1;
    __shared__ float red[2][2][2][2];
    {
        float s1 = c0, s2 = c0 * c0;
        for (int off = 32; off >= 1; off >>= 1) { s1 += __shfl_down(s1, off); s2 += __shfl_down(s2, off); }
        if (lane == 0) { red[half][wv_][0][0] = s1; red[half][wv_][0][1] = s2; }
        s1 = c1; s2 = c1 * c1;
        for (int off = 32; off >= 1; off >>= 1) { s1 += __shfl_down(s1, off); s2 += __shfl_down(s2, off); }
        if (lane == 0) { red[half][wv_][1][0] = s1; red[half][wv_][1][1] = s2; }
    }
    __syncthreads();

    const float gj = gma[j], btj = bta[j];
    #pragma unroll
    for (int q = 0; q < 2; ++q) {
        float cv = q ? c1 : c0;
        float s1 = red[half][0][q][0] + red[half][1][q][0];
        float s2 = red[half][0][q][1] + red[half][1][q][1];
        float mu = s1 * (1.0f / HH);
        float var = s2 * (1.0f / HH) - mu * mu;
        float y = (cv - mu) * rsqrtf(var + 1e-5f) * gj + btj;
        out[((size_t)(half * 2 + q) * NN + n) * HH + j] = fmaxf(y, 0.0f);
    }
}

// ---------------- GCN layer 2 + fused classifier ----------------
__global__ __launch_bounds__(256) void gcn2_cls_kernel(
    const float* __restrict__ xin,     // sA [BB][NN][HH]
    const int* __restrict__ rowptr,
    const int* __restrict__ esrc,
    const float* __restrict__ enorm,
    const float* __restrict__ Wt,      // Wt_g2
    const float* __restrict__ bias,
    const float* __restrict__ gma, const float* __restrict__ bta,
    const float* __restrict__ temporal,// [BB*NN][HH]
    const float* __restrict__ Wt1,     // Wt_c1 [256][128]
    const float* __restrict__ b1,
    const float* __restrict__ W2,      // [CC][HH]
    const float* __restrict__ b2,
    float* __restrict__ out)           // [BB][NN][CC]
{
    const int n = blockIdx.x;
    const int tid = threadIdx.x;
    const int j = tid & 127;
    const int half = tid >> 7;

    __shared__ __align__(16) float t_[BB][HH];
    for (int i = tid; i < BB * HH; i += 256) {
        int b = i >> 7, k = i & 127;
        t_[b][k] = temporal[((size_t)b * NN + n) * HH + k];
    }

    const int beg = rowptr[n], end = rowptr[n + 1];
    const int len = end - beg;
    const int mid = beg + ((len + 1) >> 1);
    int e        = half ? mid : beg;
    const int e1 = half ? end : mid;

    float a0 = 0.f, a1 = 0.f, a2 = 0.f, a3 = 0.f;
    for (; e + 1 < e1; e += 2) {
        int   s0 = esrc[e],   s1 = esrc[e + 1];
        float m0 = enorm[e],  m1 = enorm[e + 1];
        const float* p0 = xin + (size_t)s0 * HH + j;
        const float* p1 = xin + (size_t)s1 * HH + j;
        float v00 = p0[0], v01 = p0[NN*HH], v02 = p0[2*NN*HH], v03 = p0[3*NN*HH];
        float v10 = p1[0], v11 = p1[NN*HH], v12 = p1[2*NN*HH], v13 = p1[3*NN*HH];
        a0 = fmaf(m0, v00, a0); a1 = fmaf(m0, v01, a1);
        a2 = fmaf(m0, v02, a2); a3 = fmaf(m0, v03, a3);
        a0 = fmaf(m1, v10, a0); a1 = fmaf(m1, v11, a1);
        a2 = fmaf(m1, v12, a2); a3 = fmaf(m1, v13, a3);
    }
    if (e < e1) {
        int s0 = esrc[e]; float m0 = enorm[e];
        const float* p0 = xin + (size_t)s0 * HH + j;
        a0 = fmaf(m0, p0[0],       a0); a1 = fmaf(m0, p0[NN*HH],   a1);
        a2 = fmaf(m0, p0[2*NN*HH], a2); a3 = fmaf(m0, p0[3*NN*HH], a3);
    }

    __shared__ __align__(16) float agg[BB][HH];
    __shared__ __align__(16) float pagg[BB][HH];
    if (half) {
        pagg[0][j] = a0; pagg[1][j] = a1; pagg[2][j] = a2; pagg[3][j] = a3;
    }
    __syncthreads();
    if (!half) {
        agg[0][j] = a0 + pagg[0][j]; agg[1][j] = a1 + pagg[1][j];
        agg[2][j] = a2 + pagg[2][j]; agg[3][j] = a3 + pagg[3][j];
    }
    __syncthreads();

    const float bj = bias[j];
    const int b0 = half * 2, b1q = half * 2 + 1;
    float c0 = bj, c1 = bj;
    #pragma unroll 4
    for (int k = 0; k < HH; ++k) {
        float wv = Wt[k * HH + j];
        c0 = fmaf(wv, agg[b0][k], c0);
        c1 = fmaf(wv, agg[b1q][k], c1);
    }

    const int lane = tid & 63, wv_ = (tid >> 6) & 1;
    __shared__ float red[2][2][2][2];
    {
        float s1 = c0, s2 = c0 * c0;
        for (int off = 32; off >= 1; off >>= 1) { s1 += __shfl_down(s1, off); s2 += __shfl_down(s2, off); }
        if (lane == 0) { red[half][wv_][0][0] = s1; red[half][wv_][0][1] = s2; }
        s1 = c1; s2 = c1 * c1;
        for (int off = 32; off >= 1; off >>= 1) { s1 += __shfl_down(s1, off); s2 += __shfl_down(s2, off); }
        if (lane == 0) { red[half][wv_][1][0] = s1; red[half][wv_][1][1] = s2; }
    }
    __syncthreads();

    __shared__ __align__(16) float s_[BB][HH];
    const float gj = gma[j], btj = bta[j];
    #pragma unroll
    for (int q = 0; q < 2; ++q) {
        float cv = q ? c1 : c0;
        float s1 = red[half][0][q][0] + red[half][1][q][0];
        float s2 = red[half][0][q][1] + red[half][1][q][1];
        float mu = s1 * (1.0f / HH);
        float var = s2 * (1.0f / HH) - mu * mu;
        float y = (cv - mu) * rsqrtf(var + 1e-5f) * gj + btj;
        s_[half * 2 + q][j] = fmaxf(y, 0.0f);
    }
    __syncthreads();

    __shared__ __align__(16) float h1_[BB][HH];
    float h0a = b1[j], h1a = b1[j];
    #pragma unroll 4
    for (int k = 0; k < HH; ++k) {
        float wv = Wt1[k * HH + j];
        h0a = fmaf(wv, t_[b0][k],  h0a);
        h1a = fmaf(wv, t_[b1q][k], h1a);
    }
    #pragma unroll 4
    for (int k = 0; k < HH; ++k) {
        float wv = Wt1[(HH + k) * HH + j];
        h0a = fmaf(wv, s_[b0][k],  h0a);
        h1a = fmaf(wv, s_[b1q][k], h1a);
    }
    h1_[b0][j]  = fmaxf(h0a, 0.0f);
    h1_[b1q][j] = fmaxf(h1a, 0.0f);
    __syncthreads();

    if (tid < BB * CC) {
        int b = tid / CC, c = tid - b * CC;
        float a = b2[c];
        #pragma unroll 4
        for (int k = 0; k < HH; ++k) a = fmaf(W2[c * HH + k], h1_[b][k], a);
        out[((size_t)b * NN + n) * CC + c] = a;
    }
}

// ---------------- launch ----------------
extern "C" void kernel_launch(void* const* d_in, const int* in_sizes, int n_in,
                              void* d_out, int out_size, void* d_ws, size_t ws_size,
                              hipStream_t stream) {
    const float* x    = (const float*)d_in[0];
    const int*   ei   = (const int*)  d_in[1];
    const float* W_ih = (const float*)d_in[2];
    const float* W_hh = (const float*)d_in[3];
    const float* b_ih = (const float*)d_in[4];
    const float* b_hh = (const float*)d_in[5];
    const float* gW1  = (const float*)d_in[6];
    const float* gb1  = (const float*)d_in[7];
    const float* gW2  = (const float*)d_in[8];
    const float* gb2  = (const float*)d_in[9];
    const float* lg1  = (const float*)d_in[10];
    const float* lb1  = (const float*)d_in[11];
    const float* lg2  = (const float*)d_in[12];
    const float* lb2  = (const float*)d_in[13];
    const float* cW1  = (const float*)d_in[14];
    const float* cb1  = (const float*)d_in[15];
    const float* cW2  = (const float*)d_in[16];
    const float* cb2  = (const float*)d_in[17];
    float* out = (float*)d_out;

    float* ws = (float*)d_ws;
    float* Wt_g1 = ws;  ws += 128 * 128;
    float* Wt_g2 = ws;  ws += 128 * 128;
    float* Wt_c1 = ws;  ws += 256 * 128;
    float* dis   = ws;  ws += 2048;
    float* enorm = ws;  ws += EE;
    float* temporal = ws; ws += (size_t)BN * HH;
    float* sA    = ws;  ws += (size_t)BN * HH;
    int* ip      = (int*)ws;
    int* cnt     = ip;  ip += 2048;
    int* rowptr  = ip;  ip += 2080;
    int* cursor  = ip;  ip += 2048;
    int* esrc    = ip;  ip += EE;

    const int* srcp = ei;
    const int* dstp = ei + EE;

    hipMemsetAsync(cnt, 0, 2048 * sizeof(int), stream);

    prep_kernel<<<506, 256, 0, stream>>>(dstp, cnt, gW1, gW2, cW1,
                                         Wt_g1, Wt_g2, Wt_c1);
    scan_kernel<<<1, 256, 0, stream>>>(cnt, rowptr, cursor, dis);

    gru_csr_kernel<<<GRUB + EE / 512, 512, 0, stream>>>(
        x, W_hh, W_ih, b_ih, b_hh, temporal,
        srcp, dstp, dis, cursor, esrc, enorm);

    gcn_kernel<<<NN, 256, 0, stream>>>(temporal, rowptr, esrc, enorm,
                                       Wt_g1, gb1, lg1, lb1, sA);

    gcn2_cls_kernel<<<NN, 256, 0, stream>>>(sA, rowptr, esrc, enorm,
                                            Wt_g2, gb2, lg2, lb2,
                                            temporal, Wt_c1, cb1, cW2, cb2, out);
}

// Round 13
// 133.174 us; speedup vs baseline: 2.2690x; 1.0199x over previous
//
#include <hip/hip_runtime.h>
#include <math.h>

#define BB  4
#define NN  2000
#define TT  24
#define FIN 16
#define HH  128
#define EE  64000
#define CC  6
#define BN  (BB*NN)   // 8000

typedef _Float16 f16x8 __attribute__((ext_vector_type(8)));
typedef float f32x4 __attribute__((ext_vector_type(4)));

// ---------------- prep: [0..249] edge histogram (global atomics) | [250..505] transposes
// cW1 transpose also CONVERTS to fp16 (classifier weight stream was 262MB fp32/launch).
__global__ __launch_bounds__(256) void prep_kernel(
    const int* __restrict__ dst, int* __restrict__ cnt,
    const float* __restrict__ gW1, const float* __restrict__ gW2,
    const float* __restrict__ cW1,
    float* __restrict__ o1, float* __restrict__ o2, _Float16* __restrict__ o3)
{
    const int b = blockIdx.x;
    const int tid = threadIdx.x;
    if (b < 250) {
        int e = b * 256 + tid;            // 250*256 = 64000 = EE exactly
        atomicAdd(&cnt[dst[e]], 1);
    } else if (b < 314) {
        int idx = (b - 250) * 256 + tid;  // gW1 128x128
        int r = idx >> 7, c = idx & 127;
        o1[c * 128 + r] = gW1[idx];
    } else if (b < 378) {
        int idx = (b - 314) * 256 + tid;  // gW2 128x128
        int r = idx >> 7, c = idx & 127;
        o2[c * 128 + r] = gW2[idx];
    } else {
        int idx = (b - 378) * 256 + tid;  // cW1 128x256 (128 blocks), fp32 -> fp16
        int r = idx >> 8, c = idx & 255;
        o3[c * 128 + r] = (_Float16)cW1[idx];
    }
}

// single small block: scan cnt -> rowptr/cursor, dis = rsqrt(max(deg,1))
__global__ __launch_bounds__(256) void scan_kernel(
    const int* __restrict__ cnt,
    int* __restrict__ rowptr, int* __restrict__ cursor, float* __restrict__ dis)
{
    __shared__ int part[256];
    int tid = threadIdx.x;
    int base = tid * 8;
    int loc[8]; int s = 0;
    #pragma unroll
    for (int u = 0; u < 8; ++u) {
        int v = (base + u < NN) ? cnt[base + u] : 0;
        loc[u] = s; s += v;
    }
    part[tid] = s;
    __syncthreads();
    #pragma unroll
    for (int off = 1; off < 256; off <<= 1) {
        int add = (tid >= off) ? part[tid - off] : 0;
        __syncthreads();
        part[tid] += add;
        __syncthreads();
    }
    int offset = (tid > 0) ? part[tid - 1] : 0;
    #pragma unroll
    for (int u = 0; u < 8; ++u) {
        int idx = base + u;
        if (idx < NN) {
            rowptr[idx] = offset + loc[u];
            cursor[idx] = offset + loc[u];
            dis[idx] = rsqrtf(fmaxf((float)cnt[idx], 1.0f));
        }
    }
    if (tid == 255) rowptr[NN] = part[255];
}

// ---------------- GRU via MFMA + co-launched csr_fill (proven R10 structure) --------
// 500 blocks x 16 seqs; 15 MFMAs/step; fp32 hprev carry in regs. temporal now fp16
// (halves downstream gather traffic; error 2^-11 << GRU's existing 0.0078 absmax).
// NO launch_bounds min-occupancy arg (R2/R3 spill lesson).
#define HP2 136
#define GRUB 500

__global__ __launch_bounds__(512) void gru_csr_kernel(
    const float* __restrict__ x,       // [BN][TT][FIN]
    const float* __restrict__ W_hh,    // [384][128]
    const float* __restrict__ W_ih,    // [384][16]
    const float* __restrict__ b_ih, const float* __restrict__ b_hh,
    _Float16* __restrict__ t16,        // [BN][HH] fp16
    const int* __restrict__ src, const int* __restrict__ dst,
    const float* __restrict__ dis, int* __restrict__ cursor,
    int* __restrict__ esrc, float* __restrict__ enorm)
{
    const int tid  = threadIdx.x;

    if (blockIdx.x >= GRUB) {   // ---- csr_fill part (125 blocks x 512 = 64000) ----
        int e = (blockIdx.x - GRUB) * 512 + tid;
        if (e < EE) {
            int d = dst[e], s = src[e];
            int pos = atomicAdd(&cursor[d], 1);
            esrc[pos] = s;
            enorm[pos] = dis[s] * dis[d];
        }
        return;
    }

    const int lane = tid & 63;
    const int w    = tid >> 6;
    const int l15  = lane & 15;
    const int lg   = lane >> 4;
    const int m0   = blockIdx.x * 16;
    const int u    = w * 16 + l15;

    __shared__ __align__(16) unsigned short Hhi[2][16][HP2];   // 8.5 KB
    __shared__ __align__(16) unsigned short Xhi[TT][16][FIN];  // 12 KB

    f16x8 Bh[3][4];
    #pragma unroll
    for (int g = 0; g < 3; ++g) {
        const int col = g * 128 + u;
        #pragma unroll
        for (int kf = 0; kf < 4; ++kf) {
            const float* wp = W_hh + col * 128 + kf * 32 + lg * 8;
            float4 c0 = *(const float4*)wp;
            float4 c1 = *(const float4*)(wp + 4);
            f16x8 b;
            b[0] = (_Float16)c0.x; b[1] = (_Float16)c0.y;
            b[2] = (_Float16)c0.z; b[3] = (_Float16)c0.w;
            b[4] = (_Float16)c1.x; b[5] = (_Float16)c1.y;
            b[6] = (_Float16)c1.z; b[7] = (_Float16)c1.w;
            Bh[g][kf] = b;
        }
    }
    f16x8 Bi[3];
    #pragma unroll
    for (int g = 0; g < 3; ++g) {
        const int col = g * 128 + u;
        f16x8 b;
        #pragma unroll
        for (int i = 0; i < 8; ++i) b[i] = (_Float16)0.0f;
        if (lg < 2) {
            const float* wp = W_ih + col * 16 + lg * 8;
            float4 c0 = *(const float4*)wp;
            float4 c1 = *(const float4*)(wp + 4);
            b[0] = (_Float16)c0.x; b[1] = (_Float16)c0.y;
            b[2] = (_Float16)c0.z; b[3] = (_Float16)c0.w;
            b[4] = (_Float16)c1.x; b[5] = (_Float16)c1.y;
            b[6] = (_Float16)c1.z; b[7] = (_Float16)c1.w;
        } else if (lg == 2) {
            float bias = b_ih[col] + ((g < 2) ? b_hh[col] : 0.0f);
            b[0] = (_Float16)bias;   // k == 16
        }
        Bi[g] = b;
    }

    const float bhn = b_hh[256 + u];
    float hprev[4] = {0.0f, 0.0f, 0.0f, 0.0f};

    for (int i = tid; i < TT * 16 * FIN; i += 512) {
        int t   = i >> 8;
        int rem = i & 255;
        int seq = rem >> 4;
        int f   = rem & 15;
        float v = x[(size_t)(m0 + seq) * (TT * FIN) + t * FIN + f];
        _Float16 hb = (_Float16)v;
        Xhi[t][seq][f] = *(unsigned short*)&hb;
    }
    for (int i = tid; i < 16 * HP2; i += 512) (&Hhi[0][0][0])[i] = 0;
    __syncthreads();

    const f32x4 Z4 = (f32x4){0.f, 0.f, 0.f, 0.f};
    f32x4 aR, aZ, aH, aI;

#define IH_SHADOW(tt) do { \
        f16x8 axh; \
        _Float16 zz = (_Float16)0.0f; \
        axh = (f16x8){zz,zz,zz,zz,zz,zz,zz,zz}; \
        if (lg < 2) { \
            axh = *(const f16x8*)&Xhi[tt][l15][lg * 8]; \
        } else if (lg == 2) { \
            axh[0] = (_Float16)1.0f; \
        } \
        aR = __builtin_amdgcn_mfma_f32_16x16x32_f16(axh, Bi[0], Z4, 0, 0, 0); \
        aZ = __builtin_amdgcn_mfma_f32_16x16x32_f16(axh, Bi[1], Z4, 0, 0, 0); \
        aI = __builtin_amdgcn_mfma_f32_16x16x32_f16(axh, Bi[2], Z4, 0, 0, 0); \
        aH = Z4; \
    } while (0)

    IH_SHADOW(0);

    for (int t = 0; t < TT; ++t) {
        const int rb = t & 1, wb = rb ^ 1;

        #pragma unroll
        for (int kf = 0; kf < 4; ++kf) {
            const int ko = kf * 32 + lg * 8;
            f16x8 ahh = *(const f16x8*)&Hhi[rb][l15][ko];
            aR = __builtin_amdgcn_mfma_f32_16x16x32_f16(ahh, Bh[0][kf], aR, 0, 0, 0);
            aZ = __builtin_amdgcn_mfma_f32_16x16x32_f16(ahh, Bh[1][kf], aZ, 0, 0, 0);
            aH = __builtin_amdgcn_mfma_f32_16x16x32_f16(ahh, Bh[2][kf], aH, 0, 0, 0);
        }

        f32x4 aRv = aR, aZv = aZ, aHv = aH, aIv = aI;

        #pragma unroll
        for (int p = 0; p < 4; ++p) {
            float r = __builtin_amdgcn_rcpf(1.0f + __expf(-aRv[p]));
            float z = __builtin_amdgcn_rcpf(1.0f + __expf(-aZv[p]));
            float pre = fmaf(r, aHv[p] + bhn, aIv[p]);
            float e2 = __expf(2.0f * pre);
            float n = fmaf(-2.0f, __builtin_amdgcn_rcpf(e2 + 1.0f), 1.0f);
            float h = fmaf(z, hprev[p] - n, n);
            hprev[p] = h;
            _Float16 hb = (_Float16)h;
            const int seq = lg * 4 + p;
            Hhi[wb][seq][u] = *(unsigned short*)&hb;
        }

        if (t + 1 < TT) IH_SHADOW(t + 1);
        __syncthreads();
    }
#undef IH_SHADOW

    #pragma unroll
    for (int p = 0; p < 4; ++p)
        t16[(size_t)(m0 + lg * 4 + p) * HH + u] = (_Float16)hprev[p];
}

// ---------------- GCN layer 1: fp16 gather + fp32 linear/LN + fp16 out -------------
__global__ __launch_bounds__(256) void gcn_kernel(
    const _Float16* __restrict__ xin,  // [BB][NN][HH] fp16
    const int* __restrict__ rowptr,
    const int* __restrict__ esrc,
    const float* __restrict__ enorm,
    const float* __restrict__ Wt,      // [HH][HH] fp32
    const float* __restrict__ bias,
    const float* __restrict__ gma, const float* __restrict__ bta,
    _Float16* __restrict__ out)        // [BB][NN][HH] fp16
{
    const int n = blockIdx.x;
    const int tid = threadIdx.x;
    const int j = tid & 127;
    const int half = tid >> 7;
    const int beg = rowptr[n], end = rowptr[n + 1];
    const int len = end - beg;
    const int mid = beg + ((len + 1) >> 1);
    int e        = half ? mid : beg;
    const int e1 = half ? end : mid;

    float a0 = 0.f, a1 = 0.f, a2 = 0.f, a3 = 0.f;
    for (; e + 1 < e1; e += 2) {
        int   s0 = esrc[e],   s1 = esrc[e + 1];
        float m0 = enorm[e],  m1 = enorm[e + 1];
        const _Float16* p0 = xin + (size_t)s0 * HH + j;
        const _Float16* p1 = xin + (size_t)s1 * HH + j;
        float v00 = (float)p0[0], v01 = (float)p0[NN*HH];
        float v02 = (float)p0[2*NN*HH], v03 = (float)p0[3*NN*HH];
        float v10 = (float)p1[0], v11 = (float)p1[NN*HH];
        float v12 = (float)p1[2*NN*HH], v13 = (float)p1[3*NN*HH];
        a0 = fmaf(m0, v00, a0); a1 = fmaf(m0, v01, a1);
        a2 = fmaf(m0, v02, a2); a3 = fmaf(m0, v03, a3);
        a0 = fmaf(m1, v10, a0); a1 = fmaf(m1, v11, a1);
        a2 = fmaf(m1, v12, a2); a3 = fmaf(m1, v13, a3);
    }
    if (e < e1) {
        int s0 = esrc[e]; float m0 = enorm[e];
        const _Float16* p0 = xin + (size_t)s0 * HH + j;
        a0 = fmaf(m0, (float)p0[0],       a0); a1 = fmaf(m0, (float)p0[NN*HH],   a1);
        a2 = fmaf(m0, (float)p0[2*NN*HH], a2); a3 = fmaf(m0, (float)p0[3*NN*HH], a3);
    }

    __shared__ __align__(16) float agg[BB][HH];
    __shared__ __align__(16) float pagg[BB][HH];
    if (half) {
        pagg[0][j] = a0; pagg[1][j] = a1; pagg[2][j] = a2; pagg[3][j] = a3;
    }
    __syncthreads();
    if (!half) {
        agg[0][j] = a0 + pagg[0][j]; agg[1][j] = a1 + pagg[1][j];
        agg[2][j] = a2 + pagg[2][j]; agg[3][j] = a3 + pagg[3][j];
    }
    __syncthreads();

    const float bj = bias[j];
    const int b0 = half * 2, b1 = half * 2 + 1;
    float c0 = bj, c1 = bj;
    #pragma unroll 4
    for (int k = 0; k < HH; ++k) {
        float wv = Wt[k * HH + j];
        c0 = fmaf(wv, agg[b0][k], c0);
        c1 = fmaf(wv, agg[b1][k], c1);
    }

    const int lane = tid & 63, wv_ = (tid >> 6) & 1;
    __shared__ float red[2][2][2][2];
    {
        float s1 = c0, s2 = c0 * c0;
        for (int off = 32; off >= 1; off >>= 1) { s1 += __shfl_down(s1, off); s2 += __shfl_down(s2, off); }
        if (lane == 0) { red[half][wv_][0][0] = s1; red[half][wv_][0][1] = s2; }
        s1 = c1; s2 = c1 * c1;
        for (int off = 32; off >= 1; off >>= 1) { s1 += __shfl_down(s1, off); s2 += __shfl_down(s2, off); }
        if (lane == 0) { red[half][wv_][1][0] = s1; red[half][wv_][1][1] = s2; }
    }
    __syncthreads();

    const float gj = gma[j], btj = bta[j];
    #pragma unroll
    for (int q = 0; q < 2; ++q) {
        float cv = q ? c1 : c0;
        float s1 = red[half][0][q][0] + red[half][1][q][0];
        float s2 = red[half][0][q][1] + red[half][1][q][1];
        float mu = s1 * (1.0f / HH);
        float var = s2 * (1.0f / HH) - mu * mu;
        float y = (cv - mu) * rsqrtf(var + 1e-5f) * gj + btj;
        out[((size_t)(half * 2 + q) * NN + n) * HH + j] = (_Float16)fmaxf(y, 0.0f);
    }
}

// ---------------- GCN layer 2 + fused classifier (fp16 inputs/weights) -------------
__global__ __launch_bounds__(256) void gcn2_cls_kernel(
    const _Float16* __restrict__ xin,  // s16 [BB][NN][HH]
    const int* __restrict__ rowptr,
    const int* __restrict__ esrc,
    const float* __restrict__ enorm,
    const float* __restrict__ Wt,      // Wt_g2 fp32
    const float* __restrict__ bias,
    const float* __restrict__ gma, const float* __restrict__ bta,
    const _Float16* __restrict__ t16,  // [BB*NN][HH]
    const _Float16* __restrict__ Wt1,  // c16 [256][128] fp16
    const float* __restrict__ b1,
    const float* __restrict__ W2,      // [CC][HH] fp32
    const float* __restrict__ b2,
    float* __restrict__ out)           // [BB][NN][CC]
{
    const int n = blockIdx.x;
    const int tid = threadIdx.x;
    const int j = tid & 127;
    const int half = tid >> 7;

    __shared__ __align__(16) float t_[BB][HH];
    for (int i = tid; i < BB * HH; i += 256) {
        int b = i >> 7, k = i & 127;
        t_[b][k] = (float)t16[((size_t)b * NN + n) * HH + k];
    }

    const int beg = rowptr[n], end = rowptr[n + 1];
    const int len = end - beg;
    const int mid = beg + ((len + 1) >> 1);
    int e        = half ? mid : beg;
    const int e1 = half ? end : mid;

    float a0 = 0.f, a1 = 0.f, a2 = 0.f, a3 = 0.f;
    for (; e + 1 < e1; e += 2) {
        int   s0 = esrc[e],   s1 = esrc[e + 1];
        float m0 = enorm[e],  m1 = enorm[e + 1];
        const _Float16* p0 = xin + (size_t)s0 * HH + j;
        const _Float16* p1 = xin + (size_t)s1 * HH + j;
        float v00 = (float)p0[0], v01 = (float)p0[NN*HH];
        float v02 = (float)p0[2*NN*HH], v03 = (float)p0[3*NN*HH];
        float v10 = (float)p1[0], v11 = (float)p1[NN*HH];
        float v12 = (float)p1[2*NN*HH], v13 = (float)p1[3*NN*HH];
        a0 = fmaf(m0, v00, a0); a1 = fmaf(m0, v01, a1);
        a2 = fmaf(m0, v02, a2); a3 = fmaf(m0, v03, a3);
        a0 = fmaf(m1, v10, a0); a1 = fmaf(m1, v11, a1);
        a2 = fmaf(m1, v12, a2); a3 = fmaf(m1, v13, a3);
    }
    if (e < e1) {
        int s0 = esrc[e]; float m0 = enorm[e];
        const _Float16* p0 = xin + (size_t)s0 * HH + j;
        a0 = fmaf(m0, (float)p0[0],       a0); a1 = fmaf(m0, (float)p0[NN*HH],   a1);
        a2 = fmaf(m0, (float)p0[2*NN*HH], a2); a3 = fmaf(m0, (float)p0[3*NN*HH], a3);
    }

    __shared__ __align__(16) float agg[BB][HH];
    __shared__ __align__(16) float pagg[BB][HH];
    if (half) {
        pagg[0][j] = a0; pagg[1][j] = a1; pagg[2][j] = a2; pagg[3][j] = a3;
    }
    __syncthreads();
    if (!half) {
        agg[0][j] = a0 + pagg[0][j]; agg[1][j] = a1 + pagg[1][j];
        agg[2][j] = a2 + pagg[2][j]; agg[3][j] = a3 + pagg[3][j];
    }
    __syncthreads();

    const float bj = bias[j];
    const int b0 = half * 2, b1q = half * 2 + 1;
    float c0 = bj, c1 = bj;
    #pragma unroll 4
    for (int k = 0; k < HH; ++k) {
        float wv = Wt[k * HH + j];
        c0 = fmaf(wv, agg[b0][k], c0);
        c1 = fmaf(wv, agg[b1q][k], c1);
    }

    const int lane = tid & 63, wv_ = (tid >> 6) & 1;
    __shared__ float red[2][2][2][2];
    {
        float s1 = c0, s2 = c0 * c0;
        for (int off = 32; off >= 1; off >>= 1) { s1 += __shfl_down(s1, off); s2 += __shfl_down(s2, off); }
        if (lane == 0) { red[half][wv_][0][0] = s1; red[half][wv_][0][1] = s2; }
        s1 = c1; s2 = c1 * c1;
        for (int off = 32; off >= 1; off >>= 1) { s1 += __shfl_down(s1, off); s2 += __shfl_down(s2, off); }
        if (lane == 0) { red[half][wv_][1][0] = s1; red[half][wv_][1][1] = s2; }
    }
    __syncthreads();

    __shared__ __align__(16) float s_[BB][HH];
    const float gj = gma[j], btj = bta[j];
    #pragma unroll
    for (int q = 0; q < 2; ++q) {
        float cv = q ? c1 : c0;
        float s1 = red[half][0][q][0] + red[half][1][q][0];
        float s2 = red[half][0][q][1] + red[half][1][q][1];
        float mu = s1 * (1.0f / HH);
        float var = s2 * (1.0f / HH) - mu * mu;
        float y = (cv - mu) * rsqrtf(var + 1e-5f) * gj + btj;
        s_[half * 2 + q][j] = fmaxf(y, 0.0f);
    }
    __syncthreads();

    __shared__ __align__(16) float h1_[BB][HH];
    float h0a = b1[j], h1a = b1[j];
    #pragma unroll 4
    for (int k = 0; k < HH; ++k) {
        float wv = (float)Wt1[k * HH + j];
        h0a = fmaf(wv, t_[b0][k],  h0a);
        h1a = fmaf(wv, t_[b1q][k], h1a);
    }
    #pragma unroll 4
    for (int k = 0; k < HH; ++k) {
        float wv = (float)Wt1[(HH + k) * HH + j];
        h0a = fmaf(wv, s_[b0][k],  h0a);
        h1a = fmaf(wv, s_[b1q][k], h1a);
    }
    h1_[b0][j]  = fmaxf(h0a, 0.0f);
    h1_[b1q][j] = fmaxf(h1a, 0.0f);
    __syncthreads();

    if (tid < BB * CC) {
        int b = tid / CC, c = tid - b * CC;
        float a = b2[c];
        #pragma unroll 4
        for (int k = 0; k < HH; ++k) a = fmaf(W2[c * HH + k], h1_[b][k], a);
        out[((size_t)b * NN + n) * CC + c] = a;
    }
}

// ---------------- launch ----------------
extern "C" void kernel_launch(void* const* d_in, const int* in_sizes, int n_in,
                              void* d_out, int out_size, void* d_ws, size_t ws_size,
                              hipStream_t stream) {
    const float* x    = (const float*)d_in[0];
    const int*   ei   = (const int*)  d_in[1];
    const float* W_ih = (const float*)d_in[2];
    const float* W_hh = (const float*)d_in[3];
    const float* b_ih = (const float*)d_in[4];
    const float* b_hh = (const float*)d_in[5];
    const float* gW1  = (const float*)d_in[6];
    const float* gb1  = (const float*)d_in[7];
    const float* gW2  = (const float*)d_in[8];
    const float* gb2  = (const float*)d_in[9];
    const float* lg1  = (const float*)d_in[10];
    const float* lb1  = (const float*)d_in[11];
    const float* lg2  = (const float*)d_in[12];
    const float* lb2  = (const float*)d_in[13];
    const float* cW1  = (const float*)d_in[14];
    const float* cb1  = (const float*)d_in[15];
    const float* cW2  = (const float*)d_in[16];
    const float* cb2  = (const float*)d_in[17];
    float* out = (float*)d_out;

    float* ws = (float*)d_ws;
    float* Wt_g1 = ws;  ws += 128 * 128;
    float* Wt_g2 = ws;  ws += 128 * 128;
    float* dis   = ws;  ws += 2048;
    float* enorm = ws;  ws += EE;
    _Float16* t16 = (_Float16*)ws;  ws += (size_t)BN * HH / 2;
    _Float16* s16 = (_Float16*)ws;  ws += (size_t)BN * HH / 2;
    _Float16* c16 = (_Float16*)ws;  ws += 256 * 128 / 2;
    int* ip      = (int*)ws;
    int* cnt     = ip;  ip += 2048;
    int* rowptr  = ip;  ip += 2080;
    int* cursor  = ip;  ip += 2048;
    int* esrc    = ip;  ip += EE;

    const int* srcp = ei;
    const int* dstp = ei + EE;

    hipMemsetAsync(cnt, 0, 2048 * sizeof(int), stream);

    prep_kernel<<<506, 256, 0, stream>>>(dstp, cnt, gW1, gW2, cW1,
                                         Wt_g1, Wt_g2, c16);
    scan_kernel<<<1, 256, 0, stream>>>(cnt, rowptr, cursor, dis);

    gru_csr_kernel<<<GRUB + EE / 512, 512, 0, stream>>>(
        x, W_hh, W_ih, b_ih, b_hh, t16,
        srcp, dstp, dis, cursor, esrc, enorm);

    gcn_kernel<<<NN, 256, 0, stream>>>(t16, rowptr, esrc, enorm,
                                       Wt_g1, gb1, lg1, lb1, s16);

    gcn2_cls_kernel<<<NN, 256, 0, stream>>>(s16, rowptr, esrc, enorm,
                                            Wt_g2, gb2, lg2, lb2,
                                            t16, c16, cb1, cW2, cb2, out);
}

// Round 14
// 114.971 us; speedup vs baseline: 2.6282x; 1.1583x over previous
//
#include <hip/hip_runtime.h>
#include <math.h>

#define BB  4
#define NN  2000
#define TT  24
#define FIN 16
#define HH  128
#define EE  64000
#define CC  6
#define BN  (BB*NN)   // 8000

typedef _Float16 f16x8 __attribute__((ext_vector_type(8)));
typedef float f32x4 __attribute__((ext_vector_type(4)));

// ---- prep: [0..249] edge histogram | [250..313] gW2 transpose | [314..441] cW1->fp16
__global__ __launch_bounds__(256) void prep_kernel(
    const int* __restrict__ dst, int* __restrict__ cnt,
    const float* __restrict__ gW2, const float* __restrict__ cW1,
    float* __restrict__ o2, _Float16* __restrict__ o3)
{
    const int b = blockIdx.x;
    const int tid = threadIdx.x;
    if (b < 250) {
        int e = b * 256 + tid;            // 250*256 = 64000 = EE
        atomicAdd(&cnt[dst[e]], 1);
    } else if (b < 314) {
        int idx = (b - 250) * 256 + tid;  // gW2 128x128 = 64 blocks
        int r = idx >> 7, c = idx & 127;
        o2[c * 128 + r] = gW2[idx];
    } else {
        int idx = (b - 314) * 256 + tid;  // cW1 128x256 = 128 blocks, fp32 -> fp16
        int r = idx >> 8, c = idx & 255;
        o3[c * 128 + r] = (_Float16)cW1[idx];
    }
}

__global__ __launch_bounds__(256) void scan_kernel(
    const int* __restrict__ cnt,
    int* __restrict__ rowptr, int* __restrict__ cursor, float* __restrict__ dis)
{
    __shared__ int part[256];
    int tid = threadIdx.x;
    int base = tid * 8;
    int loc[8]; int s = 0;
    #pragma unroll
    for (int u = 0; u < 8; ++u) {
        int v = (base + u < NN) ? cnt[base + u] : 0;
        loc[u] = s; s += v;
    }
    part[tid] = s;
    __syncthreads();
    #pragma unroll
    for (int off = 1; off < 256; off <<= 1) {
        int add = (tid >= off) ? part[tid - off] : 0;
        __syncthreads();
        part[tid] += add;
        __syncthreads();
    }
    int offset = (tid > 0) ? part[tid - 1] : 0;
    #pragma unroll
    for (int u = 0; u < 8; ++u) {
        int idx = base + u;
        if (idx < NN) {
            rowptr[idx] = offset + loc[u];
            cursor[idx] = offset + loc[u];
            dis[idx] = rsqrtf(fmaxf((float)cnt[idx], 1.0f));
        }
    }
    if (tid == 255) rowptr[NN] = part[255];
}

// ---------------- GRU via MFMA + csr_fill + premult epilogue ----------------
// Proven R10 loop (15 MFMA/step). Epilogue: tw = h @ gW1^T via 4 MFMA/wave
// (agg(X)@W == agg(X@W), so gcn1 can gather the premultiplied rows and skip
// its 640-inst GEMV). gW1 B-frags loaded AFTER the t-loop (no live-range cost).
#define HP2 136
#define GRUB 500

__global__ __launch_bounds__(512) void gru_csr_kernel(
    const float* __restrict__ x,       // [BN][TT][FIN]
    const float* __restrict__ W_hh,    // [384][128]
    const float* __restrict__ W_ih,    // [384][16]
    const float* __restrict__ b_ih, const float* __restrict__ b_hh,
    const float* __restrict__ gW1,     // [128][128] row-major (n,k)
    _Float16* __restrict__ t16,        // [BN][HH]
    _Float16* __restrict__ tw16,       // [BN][HH]  h @ gW1^T
    const int* __restrict__ src, const int* __restrict__ dst,
    const float* __restrict__ dis, int* __restrict__ cursor,
    int* __restrict__ esrc, float* __restrict__ enorm)
{
    const int tid  = threadIdx.x;

    if (blockIdx.x >= GRUB) {   // csr_fill: 125 blocks x 512 = 64000
        int e = (blockIdx.x - GRUB) * 512 + tid;
        if (e < EE) {
            int d = dst[e], s = src[e];
            int pos = atomicAdd(&cursor[d], 1);
            esrc[pos] = s;
            enorm[pos] = dis[s] * dis[d];
        }
        return;
    }

    const int lane = tid & 63;
    const int w    = tid >> 6;
    const int l15  = lane & 15;
    const int lg   = lane >> 4;
    const int m0   = blockIdx.x * 16;
    const int u    = w * 16 + l15;

    __shared__ __align__(16) unsigned short Hhi[2][16][HP2];   // 8.5 KB
    __shared__ __align__(16) unsigned short Xhi[TT][16][FIN];  // 12 KB

    f16x8 Bh[3][4];
    #pragma unroll
    for (int g = 0; g < 3; ++g) {
        const int col = g * 128 + u;
        #pragma unroll
        for (int kf = 0; kf < 4; ++kf) {
            const float* wp = W_hh + col * 128 + kf * 32 + lg * 8;
            float4 c0 = *(const float4*)wp;
            float4 c1 = *(const float4*)(wp + 4);
            f16x8 b;
            b[0] = (_Float16)c0.x; b[1] = (_Float16)c0.y;
            b[2] = (_Float16)c0.z; b[3] = (_Float16)c0.w;
            b[4] = (_Float16)c1.x; b[5] = (_Float16)c1.y;
            b[6] = (_Float16)c1.z; b[7] = (_Float16)c1.w;
            Bh[g][kf] = b;
        }
    }
    f16x8 Bi[3];
    #pragma unroll
    for (int g = 0; g < 3; ++g) {
        const int col = g * 128 + u;
        f16x8 b;
        #pragma unroll
        for (int i = 0; i < 8; ++i) b[i] = (_Float16)0.0f;
        if (lg < 2) {
            const float* wp = W_ih + col * 16 + lg * 8;
            float4 c0 = *(const float4*)wp;
            float4 c1 = *(const float4*)(wp + 4);
            b[0] = (_Float16)c0.x; b[1] = (_Float16)c0.y;
            b[2] = (_Float16)c0.z; b[3] = (_Float16)c0.w;
            b[4] = (_Float16)c1.x; b[5] = (_Float16)c1.y;
            b[6] = (_Float16)c1.z; b[7] = (_Float16)c1.w;
        } else if (lg == 2) {
            float bias = b_ih[col] + ((g < 2) ? b_hh[col] : 0.0f);
            b[0] = (_Float16)bias;   // k == 16
        }
        Bi[g] = b;
    }

    const float bhn = b_hh[256 + u];
    float hprev[4] = {0.0f, 0.0f, 0.0f, 0.0f};

    for (int i = tid; i < TT * 16 * FIN; i += 512) {
        int t   = i >> 8;
        int rem = i & 255;
        int seq = rem >> 4;
        int f   = rem & 15;
        float v = x[(size_t)(m0 + seq) * (TT * FIN) + t * FIN + f];
        _Float16 hb = (_Float16)v;
        Xhi[t][seq][f] = *(unsigned short*)&hb;
    }
    for (int i = tid; i < 16 * HP2; i += 512) (&Hhi[0][0][0])[i] = 0;
    __syncthreads();

    const f32x4 Z4 = (f32x4){0.f, 0.f, 0.f, 0.f};
    f32x4 aR, aZ, aH, aI;

#define IH_SHADOW(tt) do { \
        f16x8 axh; \
        _Float16 zz = (_Float16)0.0f; \
        axh = (f16x8){zz,zz,zz,zz,zz,zz,zz,zz}; \
        if (lg < 2) { \
            axh = *(const f16x8*)&Xhi[tt][l15][lg * 8]; \
        } else if (lg == 2) { \
            axh[0] = (_Float16)1.0f; \
        } \
        aR = __builtin_amdgcn_mfma_f32_16x16x32_f16(axh, Bi[0], Z4, 0, 0, 0); \
        aZ = __builtin_amdgcn_mfma_f32_16x16x32_f16(axh, Bi[1], Z4, 0, 0, 0); \
        aI = __builtin_amdgcn_mfma_f32_16x16x32_f16(axh, Bi[2], Z4, 0, 0, 0); \
        aH = Z4; \
    } while (0)

    IH_SHADOW(0);

    for (int t = 0; t < TT; ++t) {
        const int rb = t & 1, wb = rb ^ 1;

        #pragma unroll
        for (int kf = 0; kf < 4; ++kf) {
            const int ko = kf * 32 + lg * 8;
            f16x8 ahh = *(const f16x8*)&Hhi[rb][l15][ko];
            aR = __builtin_amdgcn_mfma_f32_16x16x32_f16(ahh, Bh[0][kf], aR, 0, 0, 0);
            aZ = __builtin_amdgcn_mfma_f32_16x16x32_f16(ahh, Bh[1][kf], aZ, 0, 0, 0);
            aH = __builtin_amdgcn_mfma_f32_16x16x32_f16(ahh, Bh[2][kf], aH, 0, 0, 0);
        }

        f32x4 aRv = aR, aZv = aZ, aHv = aH, aIv = aI;

        #pragma unroll
        for (int p = 0; p < 4; ++p) {
            float r = __builtin_amdgcn_rcpf(1.0f + __expf(-aRv[p]));
            float z = __builtin_amdgcn_rcpf(1.0f + __expf(-aZv[p]));
            float pre = fmaf(r, aHv[p] + bhn, aIv[p]);
            float e2 = __expf(2.0f * pre);
            float n = fmaf(-2.0f, __builtin_amdgcn_rcpf(e2 + 1.0f), 1.0f);
            float h = fmaf(z, hprev[p] - n, n);
            hprev[p] = h;
            _Float16 hb = (_Float16)h;
            const int seq = lg * 4 + p;
            Hhi[wb][seq][u] = *(unsigned short*)&hb;
        }

        if (t + 1 < TT) IH_SHADOW(t + 1);
        __syncthreads();
    }
#undef IH_SHADOW

    #pragma unroll
    for (int p = 0; p < 4; ++p)
        t16[(size_t)(m0 + lg * 4 + p) * HH + u] = (_Float16)hprev[p];

    // ---- epilogue: tw = h @ gW1^T. Final h (fp16) sits in Hhi[0] (t=23 -> wb=0),
    // last __syncthreads already passed. B[k][n] = gW1[n][k]; n = w*16+l15.
    {
        f32x4 acc = Z4;
        #pragma unroll
        for (int kf = 0; kf < 4; ++kf) {
            const float* wp = gW1 + (size_t)u * 128 + kf * 32 + lg * 8;
            float4 c0 = *(const float4*)wp;
            float4 c1 = *(const float4*)(wp + 4);
            f16x8 b;
            b[0] = (_Float16)c0.x; b[1] = (_Float16)c0.y;
            b[2] = (_Float16)c0.z; b[3] = (_Float16)c0.w;
            b[4] = (_Float16)c1.x; b[5] = (_Float16)c1.y;
            b[6] = (_Float16)c1.z; b[7] = (_Float16)c1.w;
            f16x8 ah = *(const f16x8*)&Hhi[0][l15][kf * 32 + lg * 8];
            acc = __builtin_amdgcn_mfma_f32_16x16x32_f16(ah, b, acc, 0, 0, 0);
        }
        #pragma unroll
        for (int p = 0; p < 4; ++p) {
            const int row = lg * 4 + p;
            tw16[(size_t)(m0 + row) * HH + u] = (_Float16)acc[p];
        }
    }
}

// ---------------- GCN layer 1: gather(premult) + bias + LN + ReLU ------------------
__global__ __launch_bounds__(256) void gcn1_kernel(
    const _Float16* __restrict__ xin,  // tw16 [BB][NN][HH]
    const int* __restrict__ rowptr,
    const int* __restrict__ esrc,
    const float* __restrict__ enorm,
    const float* __restrict__ bias,
    const float* __restrict__ gma, const float* __restrict__ bta,
    _Float16* __restrict__ out)        // s16
{
    const int n = blockIdx.x;
    const int tid = threadIdx.x;
    const int j = tid & 127;
    const int half = tid >> 7;
    const int beg = rowptr[n], end = rowptr[n + 1];
    const int len = end - beg;
    const int mid = beg + ((len + 1) >> 1);
    int e        = half ? mid : beg;
    const int e1 = half ? end : mid;

    float a0 = 0.f, a1 = 0.f, a2 = 0.f, a3 = 0.f;
    for (; e + 1 < e1; e += 2) {
        int   s0 = esrc[e],   s1 = esrc[e + 1];
        float m0 = enorm[e],  m1 = enorm[e + 1];
        const _Float16* p0 = xin + (size_t)s0 * HH + j;
        const _Float16* p1 = xin + (size_t)s1 * HH + j;
        a0 = fmaf(m0, (float)p0[0],       a0); a1 = fmaf(m0, (float)p0[NN*HH],   a1);
        a2 = fmaf(m0, (float)p0[2*NN*HH], a2); a3 = fmaf(m0, (float)p0[3*NN*HH], a3);
        a0 = fmaf(m1, (float)p1[0],       a0); a1 = fmaf(m1, (float)p1[NN*HH],   a1);
        a2 = fmaf(m1, (float)p1[2*NN*HH], a2); a3 = fmaf(m1, (float)p1[3*NN*HH], a3);
    }
    if (e < e1) {
        int s0 = esrc[e]; float m0 = enorm[e];
        const _Float16* p0 = xin + (size_t)s0 * HH + j;
        a0 = fmaf(m0, (float)p0[0],       a0); a1 = fmaf(m0, (float)p0[NN*HH],   a1);
        a2 = fmaf(m0, (float)p0[2*NN*HH], a2); a3 = fmaf(m0, (float)p0[3*NN*HH], a3);
    }

    __shared__ __align__(16) float agg[BB][HH];
    __shared__ __align__(16) float pagg[BB][HH];
    if (half) {
        pagg[0][j] = a0; pagg[1][j] = a1; pagg[2][j] = a2; pagg[3][j] = a3;
    }
    __syncthreads();
    if (!half) {
        agg[0][j] = a0 + pagg[0][j]; agg[1][j] = a1 + pagg[1][j];
        agg[2][j] = a2 + pagg[2][j]; agg[3][j] = a3 + pagg[3][j];
    }
    __syncthreads();

    const float bj = bias[j];
    const int b0 = half * 2, b1 = half * 2 + 1;
    float c0 = agg[b0][j] + bj;
    float c1 = agg[b1][j] + bj;

    const int lane = tid & 63, wv_ = (tid >> 6) & 1;
    __shared__ float red[2][2][2][2];
    {
        float s1 = c0, s2 = c0 * c0;
        for (int off = 32; off >= 1; off >>= 1) { s1 += __shfl_down(s1, off); s2 += __shfl_down(s2, off); }
        if (lane == 0) { red[half][wv_][0][0] = s1; red[half][wv_][0][1] = s2; }
        s1 = c1; s2 = c1 * c1;
        for (int off = 32; off >= 1; off >>= 1) { s1 += __shfl_down(s1, off); s2 += __shfl_down(s2, off); }
        if (lane == 0) { red[half][wv_][1][0] = s1; red[half][wv_][1][1] = s2; }
    }
    __syncthreads();

    const float gj = gma[j], btj = bta[j];
    #pragma unroll
    for (int q = 0; q < 2; ++q) {
        float cv = q ? c1 : c0;
        float s1 = red[half][0][q][0] + red[half][1][q][0];
        float s2 = red[half][0][q][1] + red[half][1][q][1];
        float mu = s1 * (1.0f / HH);
        float var = s2 * (1.0f / HH) - mu * mu;
        float y = (cv - mu) * rsqrtf(var + 1e-5f) * gj + btj;
        out[((size_t)(half * 2 + q) * NN + n) * HH + j] = (_Float16)fmaxf(y, 0.0f);
    }
}

// ---------------- GCN layer 2: gather + W2-GEMV + LN + ReLU -> s2 fp16 -------------
__global__ __launch_bounds__(256) void gcn2_kernel(
    const _Float16* __restrict__ xin,  // s16
    const int* __restrict__ rowptr,
    const int* __restrict__ esrc,
    const float* __restrict__ enorm,
    const float* __restrict__ Wt,      // Wt_g2 fp32 [k][j]
    const float* __restrict__ bias,
    const float* __restrict__ gma, const float* __restrict__ bta,
    _Float16* __restrict__ out)        // s2_16
{
    const int n = blockIdx.x;
    const int tid = threadIdx.x;
    const int j = tid & 127;
    const int half = tid >> 7;
    const int beg = rowptr[n], end = rowptr[n + 1];
    const int len = end - beg;
    const int mid = beg + ((len + 1) >> 1);
    int e        = half ? mid : beg;
    const int e1 = half ? end : mid;

    float a0 = 0.f, a1 = 0.f, a2 = 0.f, a3 = 0.f;
    for (; e + 1 < e1; e += 2) {
        int   s0 = esrc[e],   s1 = esrc[e + 1];
        float m0 = enorm[e],  m1 = enorm[e + 1];
        const _Float16* p0 = xin + (size_t)s0 * HH + j;
        const _Float16* p1 = xin + (size_t)s1 * HH + j;
        a0 = fmaf(m0, (float)p0[0],       a0); a1 = fmaf(m0, (float)p0[NN*HH],   a1);
        a2 = fmaf(m0, (float)p0[2*NN*HH], a2); a3 = fmaf(m0, (float)p0[3*NN*HH], a3);
        a0 = fmaf(m1, (float)p1[0],       a0); a1 = fmaf(m1, (float)p1[NN*HH],   a1);
        a2 = fmaf(m1, (float)p1[2*NN*HH], a2); a3 = fmaf(m1, (float)p1[3*NN*HH], a3);
    }
    if (e < e1) {
        int s0 = esrc[e]; float m0 = enorm[e];
        const _Float16* p0 = xin + (size_t)s0 * HH + j;
        a0 = fmaf(m0, (float)p0[0],       a0); a1 = fmaf(m0, (float)p0[NN*HH],   a1);
        a2 = fmaf(m0, (float)p0[2*NN*HH], a2); a3 = fmaf(m0, (float)p0[3*NN*HH], a3);
    }

    __shared__ __align__(16) float agg[BB][HH];
    __shared__ __align__(16) float pagg[BB][HH];
    if (half) {
        pagg[0][j] = a0; pagg[1][j] = a1; pagg[2][j] = a2; pagg[3][j] = a3;
    }
    __syncthreads();
    if (!half) {
        agg[0][j] = a0 + pagg[0][j]; agg[1][j] = a1 + pagg[1][j];
        agg[2][j] = a2 + pagg[2][j]; agg[3][j] = a3 + pagg[3][j];
    }
    __syncthreads();

    const float bj = bias[j];
    const int b0 = half * 2, b1 = half * 2 + 1;
    float c0 = bj, c1 = bj;
    #pragma unroll 4
    for (int k = 0; k < HH; ++k) {
        float wv = Wt[k * HH + j];
        c0 = fmaf(wv, agg[b0][k], c0);
        c1 = fmaf(wv, agg[b1][k], c1);
    }

    const int lane = tid & 63, wv_ = (tid >> 6) & 1;
    __shared__ float red[2][2][2][2];
    {
        float s1 = c0, s2 = c0 * c0;
        for (int off = 32; off >= 1; off >>= 1) { s1 += __shfl_down(s1, off); s2 += __shfl_down(s2, off); }
        if (lane == 0) { red[half][wv_][0][0] = s1; red[half][wv_][0][1] = s2; }
        s1 = c1; s2 = c1 * c1;
        for (int off = 32; off >= 1; off >>= 1) { s1 += __shfl_down(s1, off); s2 += __shfl_down(s2, off); }
        if (lane == 0) { red[half][wv_][1][0] = s1; red[half][wv_][1][1] = s2; }
    }
    __syncthreads();

    const float gj = gma[j], btj = bta[j];
    #pragma unroll
    for (int q = 0; q < 2; ++q) {
        float cv = q ? c1 : c0;
        float s1 = red[half][0][q][0] + red[half][1][q][0];
        float s2 = red[half][0][q][1] + red[half][1][q][1];
        float mu = s1 * (1.0f / HH);
        float var = s2 * (1.0f / HH) - mu * mu;
        float y = (cv - mu) * rsqrtf(var + 1e-5f) * gj + btj;
        out[((size_t)(half * 2 + q) * NN + n) * HH + j] = (_Float16)fmaxf(y, 0.0f);
    }
}

// ---------------- classifier: MFMA over K=256 (concat t|s2), then 6-class GEMV -----
// 500 blocks x 16 rows (rows = b*NN+n flat). A-frags straight from global fp16;
// same k-map as B (k = kf*32 + lg*8 + i, kf<4 -> t16, kf>=4 -> s2). C layout:
// col=lane&15 (h1 unit within wave tile), row=(lane>>4)*4+reg.
__global__ __launch_bounds__(512) void cls_kernel(
    const _Float16* __restrict__ t16,  // [8000][128]
    const _Float16* __restrict__ s2,   // [8000][128]
    const _Float16* __restrict__ c16,  // [256][128]  c16[k][j] = cls_W1[j][k]
    const float* __restrict__ b1,
    const float* __restrict__ W2,      // [6][128]
    const float* __restrict__ b2,
    float* __restrict__ out)           // [8000][6]
{
    const int tid  = threadIdx.x;
    const int lane = tid & 63;
    const int w    = tid >> 6;
    const int l15  = lane & 15;
    const int lg   = lane >> 4;
    const int r0   = blockIdx.x * 16;
    const int u    = w * 16 + l15;     // h1 unit

    const f32x4 Z4 = (f32x4){0.f, 0.f, 0.f, 0.f};
    f32x4 acc = Z4;

    #pragma unroll
    for (int kf = 0; kf < 8; ++kf) {
        const int kl = (kf & 3) * 32 + lg * 8;
        const _Float16* ap = (kf < 4) ? (t16 + (size_t)(r0 + l15) * HH + kl)
                                      : (s2  + (size_t)(r0 + l15) * HH + kl);
        f16x8 a = *(const f16x8*)ap;
        f16x8 b;
        const int kg = kf * 32 + lg * 8;
        #pragma unroll
        for (int i = 0; i < 8; ++i) b[i] = c16[(size_t)(kg + i) * 128 + u];
        acc = __builtin_amdgcn_mfma_f32_16x16x32_f16(a, b, acc, 0, 0, 0);
    }

    __shared__ __align__(16) float h1L[16][HH];
    const float bu = b1[u];
    #pragma unroll
    for (int p = 0; p < 4; ++p) {
        const int row = lg * 4 + p;
        h1L[row][u] = fmaxf(acc[p] + bu, 0.0f);
    }
    __syncthreads();

    if (tid < 16 * CC) {
        int r = tid / CC, c = tid - r * CC;
        float a = b2[c];
        const float* wp = W2 + c * HH;
        #pragma unroll 4
        for (int k = 0; k < HH; ++k) a = fmaf(wp[k], h1L[r][k], a);
        out[(size_t)(r0 + r) * CC + c] = a;
    }
}

// ---------------- launch ----------------
extern "C" void kernel_launch(void* const* d_in, const int* in_sizes, int n_in,
                              void* d_out, int out_size, void* d_ws, size_t ws_size,
                              hipStream_t stream) {
    const float* x    = (const float*)d_in[0];
    const int*   ei   = (const int*)  d_in[1];
    const float* W_ih = (const float*)d_in[2];
    const float* W_hh = (const float*)d_in[3];
    const float* b_ih = (const float*)d_in[4];
    const float* b_hh = (const float*)d_in[5];
    const float* gW1  = (const float*)d_in[6];
    const float* gb1  = (const float*)d_in[7];
    const float* gW2  = (const float*)d_in[8];
    const float* gb2  = (const float*)d_in[9];
    const float* lg1  = (const float*)d_in[10];
    const float* lb1  = (const float*)d_in[11];
    const float* lg2  = (const float*)d_in[12];
    const float* lb2  = (const float*)d_in[13];
    const float* cW1  = (const float*)d_in[14];
    const float* cb1  = (const float*)d_in[15];
    const float* cW2  = (const float*)d_in[16];
    const float* cb2  = (const float*)d_in[17];
    float* out = (float*)d_out;

    float* ws = (float*)d_ws;
    float* Wt_g2 = ws;  ws += 128 * 128;
    float* dis   = ws;  ws += 2048;
    float* enorm = ws;  ws += EE;
    _Float16* t16  = (_Float16*)ws;  ws += (size_t)BN * HH / 2;
    _Float16* tw16 = (_Float16*)ws;  ws += (size_t)BN * HH / 2;
    _Float16* s16  = (_Float16*)ws;  ws += (size_t)BN * HH / 2;
    _Float16* s2_16= (_Float16*)ws;  ws += (size_t)BN * HH / 2;
    _Float16* c16  = (_Float16*)ws;  ws += 256 * 128 / 2;
    int* ip      = (int*)ws;
    int* cnt     = ip;  ip += 2048;
    int* rowptr  = ip;  ip += 2080;
    int* cursor  = ip;  ip += 2048;
    int* esrc    = ip;  ip += EE;

    const int* srcp = ei;
    const int* dstp = ei + EE;

    hipMemsetAsync(cnt, 0, 2048 * sizeof(int), stream);

    prep_kernel<<<442, 256, 0, stream>>>(dstp, cnt, gW2, cW1, Wt_g2, c16);
    scan_kernel<<<1, 256, 0, stream>>>(cnt, rowptr, cursor, dis);

    gru_csr_kernel<<<GRUB + EE / 512, 512, 0, stream>>>(
        x, W_hh, W_ih, b_ih, b_hh, gW1, t16, tw16,
        srcp, dstp, dis, cursor, esrc, enorm);

    gcn1_kernel<<<NN, 256, 0, stream>>>(tw16, rowptr, esrc, enorm,
                                        gb1, lg1, lb1, s16);

    gcn2_kernel<<<NN, 256, 0, stream>>>(s16, rowptr, esrc, enorm,
                                        Wt_g2, gb2, lg2, lb2, s2_16);

    cls_kernel<<<BN / 16, 512, 0, stream>>>(t16, s2_16, c16, cb1, cW2, cb2, out);
}